// Round 10
// baseline (587.501 us; speedup 1.0000x reference)
//
#include <hip/hip_runtime.h>
#include <hip/hip_fp16.h>
#include <math.h>

#define HD 64
#define EPS 1e-5f
#define BSH 9                   // bucket shift: 512 nodes per bucket
#define BSZ 512
#define T1 16384                // edges per tile in k_bucket
// packing: n <= 131072 (2^17) required: packed = (local_dst<<17) | src

__device__ __forceinline__ float atomAddF(float* p, float v) {
    return unsafeAtomicAdd(p, v);   // native global_atomic_add_f32 on gfx950
}

// ---------- CSR build (bucketed counting sort) ----------

__global__ __launch_bounds__(256) void k_bhist(const int* __restrict__ dst,
        int* __restrict__ bcnt, int e) {
    __shared__ int h[256];
    int t = threadIdx.x;
    h[t] = 0;
    __syncthreads();
    for (int i = blockIdx.x * 256 + t; i < e; i += gridDim.x * 256)
        atomicAdd(&h[dst[i] >> BSH], 1);
    __syncthreads();
    if (h[t]) atomicAdd(&bcnt[t], h[t]);
}

__global__ __launch_bounds__(256) void k_bscan(const int* __restrict__ bcnt,
        int* __restrict__ boff, int* __restrict__ gcur,
        int* __restrict__ row_ptr, int nb, int n, int e) {
    __shared__ int sc[256];
    int t = threadIdx.x;
    int v = (t < nb) ? bcnt[t] : 0;
    sc[t] = v;
    __syncthreads();
    int acc = v;
    for (int off = 1; off < 256; off <<= 1) {
        int x = (t >= off) ? sc[t - off] : 0;
        __syncthreads();
        acc += x;
        sc[t] = acc;
        __syncthreads();
    }
    int ex = acc - v;
    boff[t] = ex;                    // thread nb writes boff[nb] = e
    gcur[t] = ex;
    if (t == 0) row_ptr[n] = e;
}

__global__ __launch_bounds__(256) void k_bucket(const int* __restrict__ src,
        const int* __restrict__ dst, int* __restrict__ gcur,
        unsigned* __restrict__ bedges, int e) {
    __shared__ int hist[256];
    __shared__ int base[256];
    int t = threadIdx.x;
    for (int tile = blockIdx.x * T1; tile < e; tile += gridDim.x * T1) {
        int lim = min(e - tile, T1);
        hist[t] = 0;
        __syncthreads();
        for (int j = t; j < lim; j += 256)
            atomicAdd(&hist[dst[tile + j] >> BSH], 1);
        __syncthreads();
        int h = hist[t];
        int mybase = (h > 0) ? atomicAdd(&gcur[t], h) : 0;
        __syncthreads();
        hist[t] = 0;                 // reuse as local cursor
        base[t] = mybase;
        __syncthreads();
        for (int j = t; j < lim; j += 256) {
            int d = dst[tile + j], s = src[tile + j];
            int bk = d >> BSH;
            int loc = atomicAdd(&hist[bk], 1);
            bedges[base[bk] + loc] = ((unsigned)(d & (BSZ - 1)) << 17) | (unsigned)s;
        }
        __syncthreads();
    }
}

// pass 2: one block per bucket -> row_ptr, dinv, csr sorted by dst.
// csr keeps the PACKED word: (local512_dst<<17)|src  (aggr needs both fields)
__global__ __launch_bounds__(256) void k_build(const unsigned* __restrict__ bedges,
        const int* __restrict__ boff, int* __restrict__ row_ptr,
        unsigned* __restrict__ csr, float* __restrict__ dinv, int n) {
    __shared__ int hist[BSZ];
    __shared__ int cur[BSZ];
    __shared__ int sc[256];
    int b = blockIdx.x, t = threadIdx.x;
    int nodebase = b << BSH;
    int beg = boff[b], end = boff[b + 1];
    hist[t] = 0; hist[t + 256] = 0;
    __syncthreads();
    for (int j = beg + t; j < end; j += 256)
        atomicAdd(&hist[bedges[j] >> 17], 1);
    __syncthreads();
    int a0 = hist[2 * t], a1 = hist[2 * t + 1];
    int psum = a0 + a1;
    sc[t] = psum;
    __syncthreads();
    int acc = psum;
    for (int off = 1; off < 256; off <<= 1) {
        int x = (t >= off) ? sc[t - off] : 0;
        __syncthreads();
        acc += x;
        sc[t] = acc;
        __syncthreads();
    }
    int excl = acc - psum;           // exclusive over node pairs
    int e0 = beg + excl, e1 = beg + excl + a0;
    cur[2 * t] = e0;
    cur[2 * t + 1] = e1;
    int n0 = nodebase + 2 * t, n1 = nodebase + 2 * t + 1;
    if (n0 < n) { row_ptr[n0] = e0; dinv[n0] = rsqrtf((float)(a0 + 1)); }
    if (n1 < n) { row_ptr[n1] = e1; dinv[n1] = rsqrtf((float)(a1 + 1)); }
    __syncthreads();
    for (int j = beg + t; j < end; j += 256) {
        unsigned p = bedges[j];
        int pos = atomicAdd(&cur[p >> 17], 1);
        csr[pos] = p;
    }
}

// ---------- layer compute ----------
// A is PLANE-MAJOR: 4 planes of 16 channels; plane p row = 32B (16 halves).
// Aplane_p[n][cc] at A[p*(N<<4) + (n<<4) + cc]. One plane = 3.2MB -> L2-resident.

// A[n][c] = half( dinv[n] * sum_k x[n][k]*W0[k][c] )
__global__ __launch_bounds__(256) void k_lin0(const float* __restrict__ x,
        const float* __restrict__ W0, const float* __restrict__ dinv,
        __half* __restrict__ A, int n_nodes) {
    __shared__ float w[4 * HD];
    int t = threadIdx.x;
    w[t] = W0[t];
    __syncthreads();
    int n = blockIdx.x * 4 + (t >> 6);
    int c = t & 63;
    if (n >= n_nodes) return;
    float x0 = x[n * 4 + 0], x1 = x[n * 4 + 1], x2 = x[n * 4 + 2], x3 = x[n * 4 + 3];
    float v = x0 * w[c] + x1 * w[64 + c] + x2 * w[128 + c] + x3 * w[192 + c];
    size_t pbase = (size_t)(c >> 4) * ((size_t)n_nodes << 4);
    A[pbase + ((size_t)n << 4) + (c & 15)] = __float2half(v * dinv[n]);
}

// edge-parallel aggregation over ONE 16-channel plane (L2-resident, 3.2MB).
// One block per 64-node group; 4-lane groups: each lane loads 8B (4 halves)
// of the 32B plane row -> one wave instruction covers 16 edges; 8-deep unroll.
// Register-accumulate dst-runs (sorted), flush 4 LDS atomics on change.
__global__ __launch_bounds__(256) void k_aggr(const int* __restrict__ row_ptr,
        const unsigned* __restrict__ pedges, const __half* __restrict__ A,
        const float* __restrict__ dinv, const float* __restrict__ bias,
        float* __restrict__ B, float* __restrict__ stats, int n_nodes, int plane) {
    __shared__ float acc[64 * 17];
    __shared__ float ls[4][16], ls2[4][16];
    int t = threadIdx.x;
    for (int i = t; i < 64 * 17; i += 256) acc[i] = 0.f;
    int nodebase = blockIdx.x << 6;
    int nend = min(nodebase + 64, n_nodes);
    int ebeg = row_ptr[nodebase];
    int eend = row_ptr[nend];
    int nedges = eend - ebeg;
    __syncthreads();

    int wv = t >> 6, lane = t & 63;
    int sub = lane >> 2, ch = lane & 3;        // 4-lane group; ch*4 = channel base (in plane)
    int s = wv * 16 + sub;                     // stream 0..63
    int sbeg = ebeg + (int)(((long long)nedges * s) >> 6);
    int send = ebeg + (int)(((long long)nedges * (s + 1)) >> 6);
    const __half* Ap = A + (size_t)plane * ((size_t)n_nodes << 4);
    const uint2* A2 = (const uint2*)Ap;        // 4 uint2 per 16-half row

    float a0 = 0.f, a1 = 0.f, a2 = 0.f, a3 = 0.f;
    int cur = -1;

    #define FLUSH() if (cur >= 0) {                                            \
        int o_ = cur * 17 + (ch << 2);                                         \
        atomicAdd(&acc[o_ + 0], a0); atomicAdd(&acc[o_ + 1], a1);              \
        atomicAdd(&acc[o_ + 2], a2); atomicAdd(&acc[o_ + 3], a3); }

    #define PROC(P, U) {                                                       \
        int d_ = (int)((P) >> 17) & 63;                                        \
        if (d_ != cur) { FLUSH(); a0 = a1 = a2 = a3 = 0.f; cur = d_; }         \
        float2 f01_ = __half22float2(*(const __half2*)&(U).x);                 \
        float2 f23_ = __half22float2(*(const __half2*)&(U).y);                 \
        a0 += f01_.x; a1 += f01_.y; a2 += f23_.x; a3 += f23_.y; }

    int j = sbeg;
    for (; j + 8 <= send; j += 8) {
        unsigned p[8];
        uint2 u[8];
        #pragma unroll
        for (int k = 0; k < 8; ++k) p[k] = __builtin_nontemporal_load(&pedges[j + k]);
        #pragma unroll
        for (int k = 0; k < 8; ++k)
            u[k] = A2[(((size_t)(p[k] & 0x1FFFFu)) << 2) + ch];
        #pragma unroll
        for (int k = 0; k < 8; ++k) PROC(p[k], u[k]);
    }
    for (; j < send; ++j) {
        unsigned p0 = __builtin_nontemporal_load(&pedges[j]);
        uint2 u0 = A2[(((size_t)(p0 & 0x1FFFFu)) << 2) + ch];
        PROC(p0, u0);
    }
    FLUSH();
    #undef PROC
    #undef FLUSH
    __syncthreads();

    // finalize: wave handles 4 rows at a time (64 lanes = 4 rows x 16 ch)
    int c = lane & 15;
    int rbase = wv * 4 + (lane >> 4);          // 16 distinct rows per pass
    int cglob = (plane << 4) + c;
    float bc = bias[cglob];
    float st = 0.f, st2 = 0.f;
    for (int r = rbase; r < 64; r += 16) {
        int node = nodebase + r;
        if (node < n_nodes) {
            float v = acc[r * 17 + c] + __half2float(Ap[((size_t)node << 4) + c]);
            v = dinv[node] * v + bc;
            B[((size_t)node << 6) + cglob] = v;
            st += v; st2 += v * v;
        }
    }
    st += __shfl_xor(st, 16, 64);  st += __shfl_xor(st, 32, 64);
    st2 += __shfl_xor(st2, 16, 64); st2 += __shfl_xor(st2, 32, 64);
    if (lane < 16) { ls[wv][c] = st; ls2[wv][c] = st2; }
    __syncthreads();
    if (t < 16) {
        atomAddF(&stats[cglob - c + t],
                 ls[0][t] + ls[1][t] + ls[2][t] + ls[3][t]);
        atomAddF(&stats[64 + cglob - c + t],
                 ls2[0][t] + ls2[1][t] + ls2[2][t] + ls2[3][t]);
    }
}

// A(half, plane-major) <- dinv[n] * (relu(bn(B)) @ W1)  (BN0+ReLU fused)
__global__ __launch_bounds__(256) void k_lin1(const float* __restrict__ B,
        const float* __restrict__ W, const float* __restrict__ dinv,
        const float* __restrict__ stats, const float* __restrict__ g,
        const float* __restrict__ be, __half* __restrict__ A, int n_nodes) {
    __shared__ float w[HD * HD];
    __shared__ float rows[4][HD];
    int t = threadIdx.x;
    for (int i = t; i < HD * HD; i += 256) w[i] = W[i];
    int wv = t >> 6, c = t & 63;
    float inv_n = 1.0f / (float)n_nodes;
    float mu = stats[c] * inv_n;
    float var = stats[64 + c] * inv_n - mu * mu;
    float sc = g[c] * rsqrtf(var + EPS);
    float sh = be[c] - mu * sc;
    size_t pbase = (size_t)(c >> 4) * ((size_t)n_nodes << 4);
    int cc = c & 15;
    int ngroups = (n_nodes + 3) >> 2;
    for (int gidx = blockIdx.x; gidx < ngroups; gidx += gridDim.x) {
        __syncthreads();
        int n = gidx * 4 + wv;
        float rv = (n < n_nodes) ? fmaxf(sc * B[((size_t)n << 6) + c] + sh, 0.f) : 0.f;
        rows[wv][c] = rv;
        __syncthreads();
        if (n < n_nodes) {
            float acc = 0.f;
            #pragma unroll
            for (int k = 0; k < HD; k++) acc = fmaf(rows[wv][k], w[k * 64 + c], acc);
            A[pbase + ((size_t)n << 4) + cc] = __float2half(acc * dinv[n]);
        }
    }
}

// fused: h = relu(bn1(B)); out = sigmoid(relu(relu(h@Wm0+bm0)@Wm1+bm1)@Wm2+bm2)
__global__ __launch_bounds__(64) void k_mlp(const float* __restrict__ B,
        const float* __restrict__ stats, const float* __restrict__ g,
        const float* __restrict__ be,
        const float* __restrict__ Wm0, const float* __restrict__ bm0,
        const float* __restrict__ Wm1, const float* __restrict__ bm1,
        const float* __restrict__ Wm2, const float* __restrict__ bm2,
        float* __restrict__ out, int n_nodes) {
    __shared__ float rows[64][65];
    int t = threadIdx.x;
    float inv_n = 1.0f / (float)n_nodes;
    float mu = stats[t] * inv_n;
    float var = stats[64 + t] * inv_n - mu * mu;
    float sc = g[t] * rsqrtf(var + EPS);
    float sh = be[t] - mu * sc;
    int nbase = blockIdx.x * 64;
    #pragma unroll 4
    for (int r = 0; r < 64; r++) {
        int nn = nbase + r;
        rows[r][t] = (nn < n_nodes) ? fmaxf(sc * B[((size_t)nn << 6) + t] + sh, 0.f) : 0.f;
    }
    __syncthreads();
    int n = nbase + t;
    if (n >= n_nodes) return;

    float a1[64];
    #pragma unroll
    for (int cc = 0; cc < 4; ++cc) {
        float acc[16];
        #pragma unroll
        for (int j = 0; j < 16; ++j) acc[j] = bm0[cc * 16 + j];
        for (int k = 0; k < 64; ++k) {
            float hv = rows[t][k];
            #pragma unroll
            for (int j = 0; j < 16; ++j)
                acc[j] = fmaf(hv, Wm0[k * 64 + cc * 16 + j], acc[j]);
        }
        #pragma unroll
        for (int j = 0; j < 16; ++j) a1[cc * 16 + j] = fmaxf(acc[j], 0.f);
    }
    #pragma unroll
    for (int k = 0; k < 64; ++k) rows[t][k] = a1[k];

    float a2[32];
    #pragma unroll
    for (int cc = 0; cc < 2; ++cc) {
        float acc[16];
        #pragma unroll
        for (int j = 0; j < 16; ++j) acc[j] = bm1[cc * 16 + j];
        for (int k = 0; k < 64; ++k) {
            float hv = rows[t][k];
            #pragma unroll
            for (int j = 0; j < 16; ++j)
                acc[j] = fmaf(hv, Wm1[k * 32 + cc * 16 + j], acc[j]);
        }
        #pragma unroll
        for (int j = 0; j < 16; ++j) a2[cc * 16 + j] = fmaxf(acc[j], 0.f);
    }
    float z = bm2[0];
    #pragma unroll
    for (int k = 0; k < 32; ++k) z = fmaf(a2[k], Wm2[k], z);
    out[n] = 1.0f / (1.0f + __expf(-z));
}

extern "C" void kernel_launch(void* const* d_in, const int* in_sizes, int n_in,
                              void* d_out, int out_size, void* d_ws, size_t ws_size,
                              hipStream_t stream) {
    const float* x   = (const float*)d_in[0];
    const int*   src = (const int*)d_in[1];
    const int*   dst = (const int*)d_in[2];
    const float* W0  = (const float*)d_in[3];
    const float* b0  = (const float*)d_in[4];
    const float* W1  = (const float*)d_in[5];
    const float* b1  = (const float*)d_in[6];
    const float* g0  = (const float*)d_in[7];
    const float* be0 = (const float*)d_in[8];
    const float* g1  = (const float*)d_in[9];
    const float* be1 = (const float*)d_in[10];
    const float* Wm0 = (const float*)d_in[11];
    const float* bm0 = (const float*)d_in[12];
    const float* Wm1 = (const float*)d_in[13];
    const float* bm1 = (const float*)d_in[14];
    const float* Wm2 = (const float*)d_in[15];
    const float* bm2 = (const float*)d_in[16];

    int n = in_sizes[0] / 4;
    int e = in_sizes[1];
    float* out = (float*)d_out;

    char* ws = (char*)d_ws;
    auto alignup = [](size_t v) { return (v + 255) & ~(size_t)255; };
    size_t o = 0;
    int*      bcnt    = (int*)(ws + o);      o += alignup(256 * 4);
    int*      boff    = (int*)(ws + o);      o += alignup(257 * 4);
    int*      gcur    = (int*)(ws + o);      o += alignup(256 * 4);
    float*    stats   = (float*)(ws + o);    o += alignup(256 * 4);
    int*      row_ptr = (int*)(ws + o);      o += alignup((size_t)(n + 1) * 4);
    float*    dinv    = (float*)(ws + o);    o += alignup((size_t)n * 4);
    unsigned* bedges  = (unsigned*)(ws + o); o += alignup((size_t)e * 4);
    unsigned* csr     = (unsigned*)(ws + o); o += alignup((size_t)e * 4);
    __half*   A       = (__half*)(ws + o);   o += alignup((size_t)n * 64 * 2);
    float*    B       = (float*)(ws + o);

    int nb     = (n + BSZ - 1) >> BSH;        // 196 buckets for n=100k (requires n<=131072)
    int gN4    = (n + 3) / 4;
    int ntiles = (e + T1 - 1) / T1;
    int gMLP   = (n + 63) / 64;
    int gAGG   = (n + 63) / 64;               // one block per 64-node group

    (void)hipMemsetAsync(bcnt, 0, 256 * 4, stream);
    (void)hipMemsetAsync(stats, 0, 256 * 4, stream);

    // ---- CSR build (bucketed, once, reused by both layers) ----
    k_bhist<<<512, 256, 0, stream>>>(dst, bcnt, e);
    k_bscan<<<1, 256, 0, stream>>>(bcnt, boff, gcur, row_ptr, nb, n, e);
    k_bucket<<<ntiles, 256, 0, stream>>>(src, dst, gcur, bedges, e);
    k_build<<<nb, 256, 0, stream>>>(bedges, boff, row_ptr, csr, dinv, n);

    // ---- layer 1 ----
    k_lin0<<<gN4, 256, 0, stream>>>(x, W0, dinv, A, n);
    for (int p = 0; p < 4; ++p)
        k_aggr<<<gAGG, 256, 0, stream>>>(row_ptr, csr, A, dinv, b0, B, stats, n, p);

    // ---- layer 2 (BN0+ReLU fused into lin1) ----
    k_lin1<<<2048, 256, 0, stream>>>(B, W1, dinv, stats, g0, be0, A, n);
    for (int p = 0; p < 4; ++p)
        k_aggr<<<gAGG, 256, 0, stream>>>(row_ptr, csr, A, dinv, b1, B, stats + 128, n, p);

    // ---- MLP head (BN1+ReLU fused) ----
    k_mlp<<<gMLP, 64, 0, stream>>>(B, stats + 128, g1, be1,
                                   Wm0, bm0, Wm1, bm1, Wm2, bm2, out, n);
}

// Round 11
// 437.650 us; speedup vs baseline: 1.3424x; 1.3424x over previous
//
#include <hip/hip_runtime.h>
#include <hip/hip_fp16.h>
#include <math.h>

#define HD 64
#define EPS 1e-5f
#define BSH 9                   // bucket shift: 512 nodes per bucket
#define BSZ 512
#define T1 4096                 // edges per tile in k_bucket (782 blocks)
// packing: n <= 131072 (2^17) required: packed = (local_dst<<17) | src

__device__ __forceinline__ float atomAddF(float* p, float v) {
    return unsafeAtomicAdd(p, v);   // native global_atomic_add_f32 on gfx950
}

// ---------- CSR build (bucketed counting sort) ----------

__global__ __launch_bounds__(256) void k_bhist(const int* __restrict__ dst,
        int* __restrict__ bcnt, int e) {
    __shared__ int h[256];
    int t = threadIdx.x;
    h[t] = 0;
    __syncthreads();
    for (int i = blockIdx.x * 256 + t; i < e; i += gridDim.x * 256)
        atomicAdd(&h[dst[i] >> BSH], 1);
    __syncthreads();
    if (h[t]) atomicAdd(&bcnt[t], h[t]);
}

__global__ __launch_bounds__(256) void k_bscan(const int* __restrict__ bcnt,
        int* __restrict__ boff, int* __restrict__ gcur,
        int* __restrict__ row_ptr, int nb, int n, int e) {
    __shared__ int sc[256];
    int t = threadIdx.x;
    int v = (t < nb) ? bcnt[t] : 0;
    sc[t] = v;
    __syncthreads();
    int acc = v;
    for (int off = 1; off < 256; off <<= 1) {
        int x = (t >= off) ? sc[t - off] : 0;
        __syncthreads();
        acc += x;
        sc[t] = acc;
        __syncthreads();
    }
    int ex = acc - v;
    boff[t] = ex;                    // thread nb writes boff[nb] = e
    gcur[t] = ex;
    if (t == 0) row_ptr[n] = e;
}

__global__ __launch_bounds__(256) void k_bucket(const int* __restrict__ src,
        const int* __restrict__ dst, int* __restrict__ gcur,
        unsigned* __restrict__ bedges, int e) {
    __shared__ int hist[256];
    __shared__ int base[256];
    int t = threadIdx.x;
    for (int tile = blockIdx.x * T1; tile < e; tile += gridDim.x * T1) {
        int lim = min(e - tile, T1);
        hist[t] = 0;
        __syncthreads();
        for (int j = t; j < lim; j += 256)
            atomicAdd(&hist[dst[tile + j] >> BSH], 1);
        __syncthreads();
        int h = hist[t];
        int mybase = (h > 0) ? atomicAdd(&gcur[t], h) : 0;
        __syncthreads();
        hist[t] = 0;                 // reuse as local cursor
        base[t] = mybase;
        __syncthreads();
        for (int j = t; j < lim; j += 256) {
            int d = dst[tile + j], s = src[tile + j];
            int bk = d >> BSH;
            int loc = atomicAdd(&hist[bk], 1);
            bedges[base[bk] + loc] = ((unsigned)(d & (BSZ - 1)) << 17) | (unsigned)s;
        }
        __syncthreads();
    }
}

// pass 2: one block per bucket -> row_ptr, dinv, csr sorted by dst.
// csr keeps the PACKED word: (local512_dst<<17)|src  (aggr needs both fields)
__global__ __launch_bounds__(256) void k_build(const unsigned* __restrict__ bedges,
        const int* __restrict__ boff, int* __restrict__ row_ptr,
        unsigned* __restrict__ csr, float* __restrict__ dinv, int n) {
    __shared__ int hist[BSZ];
    __shared__ int cur[BSZ];
    __shared__ int sc[256];
    int b = blockIdx.x, t = threadIdx.x;
    int nodebase = b << BSH;
    int beg = boff[b], end = boff[b + 1];
    hist[t] = 0; hist[t + 256] = 0;
    __syncthreads();
    for (int j = beg + t; j < end; j += 256)
        atomicAdd(&hist[bedges[j] >> 17], 1);
    __syncthreads();
    int a0 = hist[2 * t], a1 = hist[2 * t + 1];
    int psum = a0 + a1;
    sc[t] = psum;
    __syncthreads();
    int acc = psum;
    for (int off = 1; off < 256; off <<= 1) {
        int x = (t >= off) ? sc[t - off] : 0;
        __syncthreads();
        acc += x;
        sc[t] = acc;
        __syncthreads();
    }
    int excl = acc - psum;           // exclusive over node pairs
    int e0 = beg + excl, e1 = beg + excl + a0;
    cur[2 * t] = e0;
    cur[2 * t + 1] = e1;
    int n0 = nodebase + 2 * t, n1 = nodebase + 2 * t + 1;
    if (n0 < n) { row_ptr[n0] = e0; dinv[n0] = rsqrtf((float)(a0 + 1)); }
    if (n1 < n) { row_ptr[n1] = e1; dinv[n1] = rsqrtf((float)(a1 + 1)); }
    __syncthreads();
    for (int j = beg + t; j < end; j += 256) {
        unsigned p = bedges[j];
        int pos = atomicAdd(&cur[p >> 17], 1);
        csr[pos] = p;
    }
}

// ---------- layer compute ----------
// A: fp16, linear rows A[n*64+c] (128B per row)

// A[n][c] = half( dinv[n] * sum_k x[n][k]*W0[k][c] )
__global__ __launch_bounds__(256) void k_lin0(const float* __restrict__ x,
        const float* __restrict__ W0, const float* __restrict__ dinv,
        __half* __restrict__ A, int n_nodes) {
    __shared__ float w[4 * HD];
    int t = threadIdx.x;
    w[t] = W0[t];
    __syncthreads();
    int n = blockIdx.x * 4 + (t >> 6);
    int c = t & 63;
    if (n >= n_nodes) return;
    float x0 = x[n * 4 + 0], x1 = x[n * 4 + 1], x2 = x[n * 4 + 2], x3 = x[n * 4 + 3];
    float v = x0 * w[c] + x1 * w[64 + c] + x2 * w[128 + c] + x3 * w[192 + c];
    A[((size_t)n << 6) + c] = __float2half(v * dinv[n]);
}

// edge-parallel aggregation: one block per 32-node group, fp32 LDS accumulator.
// 16-lane groups: each lane loads 8B (4 halves) of the 128B row -> one wave
// instruction covers 4 edges; 8-deep unroll -> 8 gathers in flight per group.
// Register-accumulate runs of equal dst (sorted), flush 4 LDS atomics on change.
__global__ __launch_bounds__(256) void k_aggr(const int* __restrict__ row_ptr,
        const unsigned* __restrict__ pedges, const __half* __restrict__ A,
        const float* __restrict__ dinv, const float* __restrict__ bias,
        float* __restrict__ B, float* __restrict__ stats, int n_nodes) {
    __shared__ float acc[32 * 65];
    __shared__ float ls[4][64], ls2[4][64];
    int t = threadIdx.x;
    for (int i = t; i < 32 * 65; i += 256) acc[i] = 0.f;
    int nodebase = blockIdx.x << 5;
    int nend = min(nodebase + 32, n_nodes);
    int ebeg = row_ptr[nodebase];
    int eend = row_ptr[nend];
    int nedges = eend - ebeg;
    __syncthreads();

    int wv = t >> 6, lane = t & 63;
    int sub = lane >> 4, ch = lane & 15;       // 16-lane group; ch*4 = channel base
    int s = wv * 4 + sub;                      // stream 0..15
    int sbeg = ebeg + (int)(((long long)nedges * s) >> 4);
    int send = ebeg + (int)(((long long)nedges * (s + 1)) >> 4);
    const uint2* A2 = (const uint2*)A;         // 16 uint2 per 64-half row

    float a0 = 0.f, a1 = 0.f, a2 = 0.f, a3 = 0.f;
    int cur = -1;

    #define FLUSH() if (cur >= 0) {                                            \
        int o_ = cur * 65 + (ch << 2);                                         \
        atomicAdd(&acc[o_ + 0], a0); atomicAdd(&acc[o_ + 1], a1);              \
        atomicAdd(&acc[o_ + 2], a2); atomicAdd(&acc[o_ + 3], a3); }

    #define PROC(P, U) {                                                       \
        int d_ = (int)((P) >> 17) & 31;                                        \
        if (d_ != cur) { FLUSH(); a0 = a1 = a2 = a3 = 0.f; cur = d_; }         \
        float2 f01_ = __half22float2(*(const __half2*)&(U).x);                 \
        float2 f23_ = __half22float2(*(const __half2*)&(U).y);                 \
        a0 += f01_.x; a1 += f01_.y; a2 += f23_.x; a3 += f23_.y; }

    int j = sbeg;
    for (; j + 8 <= send; j += 8) {
        unsigned p[8];
        uint2 u[8];
        #pragma unroll
        for (int k = 0; k < 8; ++k) p[k] = pedges[j + k];
        #pragma unroll
        for (int k = 0; k < 8; ++k)
            u[k] = A2[(((size_t)(p[k] & 0x1FFFFu)) << 4) + ch];
        #pragma unroll
        for (int k = 0; k < 8; ++k) PROC(p[k], u[k]);
    }
    for (; j < send; ++j) {
        unsigned p0 = pedges[j];
        uint2 u0 = A2[(((size_t)(p0 & 0x1FFFFu)) << 4) + ch];
        PROC(p0, u0);
    }
    FLUSH();
    #undef PROC
    #undef FLUSH
    __syncthreads();

    // finalize: wave wv handles rows wv, wv+4, ... ; lane = channel
    int c = lane;
    float st = 0.f, st2 = 0.f;
    for (int r = wv; r < 32; r += 4) {
        int node = nodebase + r;
        if (node < n_nodes) {
            float v = acc[r * 65 + c] + __half2float(A[((size_t)node << 6) + c]);
            v = dinv[node] * v + bias[c];
            B[((size_t)node << 6) + c] = v;
            st += v; st2 += v * v;
        }
    }
    ls[wv][c] = st; ls2[wv][c] = st2;
    __syncthreads();
    if (t < 64) {
        atomAddF(&stats[t], ls[0][t] + ls[1][t] + ls[2][t] + ls[3][t]);
        atomAddF(&stats[64 + t], ls2[0][t] + ls2[1][t] + ls2[2][t] + ls2[3][t]);
    }
}

// A(half) <- dinv[n] * (relu(bn(B)) @ W1)   (BN0+ReLU fused into row staging)
__global__ __launch_bounds__(256) void k_lin1(const float* __restrict__ B,
        const float* __restrict__ W, const float* __restrict__ dinv,
        const float* __restrict__ stats, const float* __restrict__ g,
        const float* __restrict__ be, __half* __restrict__ A, int n_nodes) {
    __shared__ float w[HD * HD];
    __shared__ float rows[4][HD];
    int t = threadIdx.x;
    for (int i = t; i < HD * HD; i += 256) w[i] = W[i];
    int wv = t >> 6, c = t & 63;
    float inv_n = 1.0f / (float)n_nodes;
    float mu = stats[c] * inv_n;
    float var = stats[64 + c] * inv_n - mu * mu;
    float sc = g[c] * rsqrtf(var + EPS);
    float sh = be[c] - mu * sc;
    int ngroups = (n_nodes + 3) >> 2;
    for (int gidx = blockIdx.x; gidx < ngroups; gidx += gridDim.x) {
        __syncthreads();
        int n = gidx * 4 + wv;
        float rv = (n < n_nodes) ? fmaxf(sc * B[((size_t)n << 6) + c] + sh, 0.f) : 0.f;
        rows[wv][c] = rv;
        __syncthreads();
        if (n < n_nodes) {
            float acc = 0.f;
            #pragma unroll
            for (int k = 0; k < HD; k++) acc = fmaf(rows[wv][k], w[k * 64 + c], acc);
            A[((size_t)n << 6) + c] = __float2half(acc * dinv[n]);
        }
    }
}

// fused: h = relu(bn1(B)); out = sigmoid(relu(relu(h@Wm0+bm0)@Wm1+bm1)@Wm2+bm2)
// 256-thread blocks: 4 waves, each wave stages+owns 64 nodes in its own LDS slab
__global__ __launch_bounds__(256) void k_mlp(const float* __restrict__ B,
        const float* __restrict__ stats, const float* __restrict__ g,
        const float* __restrict__ be,
        const float* __restrict__ Wm0, const float* __restrict__ bm0,
        const float* __restrict__ Wm1, const float* __restrict__ bm1,
        const float* __restrict__ Wm2, const float* __restrict__ bm2,
        float* __restrict__ out, int n_nodes) {
    __shared__ float rows[4][64][65];
    int t = threadIdx.x;
    int w = t >> 6, lane = t & 63;
    float inv_n = 1.0f / (float)n_nodes;
    float mu = stats[lane] * inv_n;
    float var = stats[64 + lane] * inv_n - mu * mu;
    float sc = g[lane] * rsqrtf(var + EPS);
    float sh = be[lane] - mu * sc;
    int nbase = blockIdx.x * 256 + w * 64;
    #pragma unroll 4
    for (int r = 0; r < 64; r++) {
        int nn = nbase + r;
        rows[w][r][lane] = (nn < n_nodes) ? fmaxf(sc * B[((size_t)nn << 6) + lane] + sh, 0.f) : 0.f;
    }
    __syncthreads();
    int n = nbase + lane;
    if (n >= n_nodes) return;

    float a1[64];
    #pragma unroll
    for (int cc = 0; cc < 4; ++cc) {
        float acc[16];
        #pragma unroll
        for (int j = 0; j < 16; ++j) acc[j] = bm0[cc * 16 + j];
        for (int k = 0; k < 64; ++k) {
            float hv = rows[w][lane][k];
            #pragma unroll
            for (int j = 0; j < 16; ++j)
                acc[j] = fmaf(hv, Wm0[k * 64 + cc * 16 + j], acc[j]);
        }
        #pragma unroll
        for (int j = 0; j < 16; ++j) a1[cc * 16 + j] = fmaxf(acc[j], 0.f);
    }
    // park a1 in own LDS row (private; no barrier needed)
    #pragma unroll
    for (int k = 0; k < 64; ++k) rows[w][lane][k] = a1[k];

    float a2[32];
    #pragma unroll
    for (int cc = 0; cc < 2; ++cc) {
        float acc[16];
        #pragma unroll
        for (int j = 0; j < 16; ++j) acc[j] = bm1[cc * 16 + j];
        for (int k = 0; k < 64; ++k) {
            float hv = rows[w][lane][k];
            #pragma unroll
            for (int j = 0; j < 16; ++j)
                acc[j] = fmaf(hv, Wm1[k * 32 + cc * 16 + j], acc[j]);
        }
        #pragma unroll
        for (int j = 0; j < 16; ++j) a2[cc * 16 + j] = fmaxf(acc[j], 0.f);
    }
    float z = bm2[0];
    #pragma unroll
    for (int k = 0; k < 32; ++k) z = fmaf(a2[k], Wm2[k], z);
    out[n] = 1.0f / (1.0f + __expf(-z));
}

extern "C" void kernel_launch(void* const* d_in, const int* in_sizes, int n_in,
                              void* d_out, int out_size, void* d_ws, size_t ws_size,
                              hipStream_t stream) {
    const float* x   = (const float*)d_in[0];
    const int*   src = (const int*)d_in[1];
    const int*   dst = (const int*)d_in[2];
    const float* W0  = (const float*)d_in[3];
    const float* b0  = (const float*)d_in[4];
    const float* W1  = (const float*)d_in[5];
    const float* b1  = (const float*)d_in[6];
    const float* g0  = (const float*)d_in[7];
    const float* be0 = (const float*)d_in[8];
    const float* g1  = (const float*)d_in[9];
    const float* be1 = (const float*)d_in[10];
    const float* Wm0 = (const float*)d_in[11];
    const float* bm0 = (const float*)d_in[12];
    const float* Wm1 = (const float*)d_in[13];
    const float* bm1 = (const float*)d_in[14];
    const float* Wm2 = (const float*)d_in[15];
    const float* bm2 = (const float*)d_in[16];

    int n = in_sizes[0] / 4;
    int e = in_sizes[1];
    float* out = (float*)d_out;

    char* ws = (char*)d_ws;
    auto alignup = [](size_t v) { return (v + 255) & ~(size_t)255; };
    size_t o = 0;
    int*      bcnt    = (int*)(ws + o);      o += alignup(256 * 4);
    int*      boff    = (int*)(ws + o);      o += alignup(257 * 4);
    int*      gcur    = (int*)(ws + o);      o += alignup(256 * 4);
    float*    stats   = (float*)(ws + o);    o += alignup(256 * 4);
    int*      row_ptr = (int*)(ws + o);      o += alignup((size_t)(n + 1) * 4);
    float*    dinv    = (float*)(ws + o);    o += alignup((size_t)n * 4);
    unsigned* bedges  = (unsigned*)(ws + o); o += alignup((size_t)e * 4);
    unsigned* csr     = (unsigned*)(ws + o); o += alignup((size_t)e * 4);
    __half*   A       = (__half*)(ws + o);   o += alignup((size_t)n * 64 * 2);
    float*    B       = (float*)(ws + o);

    int nb     = (n + BSZ - 1) >> BSH;        // 196 buckets for n=100k (requires n<=131072)
    int gN4    = (n + 3) / 4;
    int ntiles = (e + T1 - 1) / T1;           // 782 blocks
    int gMLP   = (n + 255) / 256;
    int gAGG   = (n + 31) / 32;               // one block per 32-node group

    (void)hipMemsetAsync(bcnt, 0, 256 * 4, stream);
    (void)hipMemsetAsync(stats, 0, 256 * 4, stream);

    // ---- CSR build (bucketed, once, reused by both layers) ----
    k_bhist<<<512, 256, 0, stream>>>(dst, bcnt, e);
    k_bscan<<<1, 256, 0, stream>>>(bcnt, boff, gcur, row_ptr, nb, n, e);
    k_bucket<<<ntiles, 256, 0, stream>>>(src, dst, gcur, bedges, e);
    k_build<<<nb, 256, 0, stream>>>(bedges, boff, row_ptr, csr, dinv, n);

    // ---- layer 1 ----
    k_lin0<<<gN4, 256, 0, stream>>>(x, W0, dinv, A, n);
    k_aggr<<<gAGG, 256, 0, stream>>>(row_ptr, csr, A, dinv, b0, B, stats, n);

    // ---- layer 2 (BN0+ReLU fused into lin1) ----
    k_lin1<<<2048, 256, 0, stream>>>(B, W1, dinv, stats, g0, be0, A, n);
    k_aggr<<<gAGG, 256, 0, stream>>>(row_ptr, csr, A, dinv, b1, B, stats + 128, n);

    // ---- MLP head (BN1+ReLU fused) ----
    k_mlp<<<gMLP, 256, 0, stream>>>(B, stats + 128, g1, be1,
                                    Wm0, bm0, Wm1, bm1, Wm2, bm2, out, n);
}

// Round 12
// 395.586 us; speedup vs baseline: 1.4851x; 1.1063x over previous
//
#include <hip/hip_runtime.h>
#include <hip/hip_fp16.h>
#include <math.h>

#define HD 64
#define EPS 1e-5f
#define BSH 9                   // bucket shift: 512 nodes per bucket
#define BSZ 512
#define T1 16384                // edges per tile in k_bucket
// packing: n <= 131072 (2^17) required: packed = (local_dst<<17) | src

__device__ __forceinline__ float atomAddF(float* p, float v) {
    return unsafeAtomicAdd(p, v);   // native global_atomic_add_f32 on gfx950
}

// ---------- CSR build (bucketed counting sort) ----------

__global__ __launch_bounds__(256) void k_bhist(const int* __restrict__ dst,
        int* __restrict__ bcnt, int e) {
    __shared__ int h[256];
    int t = threadIdx.x;
    h[t] = 0;
    __syncthreads();
    for (int i = blockIdx.x * 256 + t; i < e; i += gridDim.x * 256)
        atomicAdd(&h[dst[i] >> BSH], 1);
    __syncthreads();
    if (h[t]) atomicAdd(&bcnt[t], h[t]);
}

__global__ __launch_bounds__(256) void k_bscan(const int* __restrict__ bcnt,
        int* __restrict__ boff, int* __restrict__ gcur,
        int* __restrict__ row_ptr, int nb, int n, int e) {
    __shared__ int sc[256];
    int t = threadIdx.x;
    int v = (t < nb) ? bcnt[t] : 0;
    sc[t] = v;
    __syncthreads();
    int acc = v;
    for (int off = 1; off < 256; off <<= 1) {
        int x = (t >= off) ? sc[t - off] : 0;
        __syncthreads();
        acc += x;
        sc[t] = acc;
        __syncthreads();
    }
    int ex = acc - v;
    boff[t] = ex;                    // thread nb writes boff[nb] = e
    gcur[t] = ex;
    if (t == 0) row_ptr[n] = e;
}

__global__ __launch_bounds__(256) void k_bucket(const int* __restrict__ src,
        const int* __restrict__ dst, int* __restrict__ gcur,
        unsigned* __restrict__ bedges, int e) {
    __shared__ int hist[256];
    __shared__ int base[256];
    int t = threadIdx.x;
    for (int tile = blockIdx.x * T1; tile < e; tile += gridDim.x * T1) {
        int lim = min(e - tile, T1);
        hist[t] = 0;
        __syncthreads();
        for (int j = t; j < lim; j += 256)
            atomicAdd(&hist[dst[tile + j] >> BSH], 1);
        __syncthreads();
        int h = hist[t];
        int mybase = (h > 0) ? atomicAdd(&gcur[t], h) : 0;
        __syncthreads();
        hist[t] = 0;                 // reuse as local cursor
        base[t] = mybase;
        __syncthreads();
        for (int j = t; j < lim; j += 256) {
            int d = dst[tile + j], s = src[tile + j];
            int bk = d >> BSH;
            int loc = atomicAdd(&hist[bk], 1);
            bedges[base[bk] + loc] = ((unsigned)(d & (BSZ - 1)) << 17) | (unsigned)s;
        }
        __syncthreads();
    }
}

// pass 2: one block per bucket -> row_ptr, dinv, csr sorted by dst.
// csr keeps the PACKED word: (local512_dst<<17)|src  (aggr needs both fields)
__global__ __launch_bounds__(256) void k_build(const unsigned* __restrict__ bedges,
        const int* __restrict__ boff, int* __restrict__ row_ptr,
        unsigned* __restrict__ csr, float* __restrict__ dinv, int n) {
    __shared__ int hist[BSZ];
    __shared__ int cur[BSZ];
    __shared__ int sc[256];
    int b = blockIdx.x, t = threadIdx.x;
    int nodebase = b << BSH;
    int beg = boff[b], end = boff[b + 1];
    hist[t] = 0; hist[t + 256] = 0;
    __syncthreads();
    for (int j = beg + t; j < end; j += 256)
        atomicAdd(&hist[bedges[j] >> 17], 1);
    __syncthreads();
    int a0 = hist[2 * t], a1 = hist[2 * t + 1];
    int psum = a0 + a1;
    sc[t] = psum;
    __syncthreads();
    int acc = psum;
    for (int off = 1; off < 256; off <<= 1) {
        int x = (t >= off) ? sc[t - off] : 0;
        __syncthreads();
        acc += x;
        sc[t] = acc;
        __syncthreads();
    }
    int excl = acc - psum;           // exclusive over node pairs
    int e0 = beg + excl, e1 = beg + excl + a0;
    cur[2 * t] = e0;
    cur[2 * t + 1] = e1;
    int n0 = nodebase + 2 * t, n1 = nodebase + 2 * t + 1;
    if (n0 < n) { row_ptr[n0] = e0; dinv[n0] = rsqrtf((float)(a0 + 1)); }
    if (n1 < n) { row_ptr[n1] = e1; dinv[n1] = rsqrtf((float)(a1 + 1)); }
    __syncthreads();
    for (int j = beg + t; j < end; j += 256) {
        unsigned p = bedges[j];
        int pos = atomicAdd(&cur[p >> 17], 1);
        csr[pos] = p;
    }
}

// ---------- layer compute ----------
// A: fp16, linear rows A[n*64+c] (128B per row)

// A[n][c] = half( dinv[n] * sum_k x[n][k]*W0[k][c] )
__global__ __launch_bounds__(256) void k_lin0(const float* __restrict__ x,
        const float* __restrict__ W0, const float* __restrict__ dinv,
        __half* __restrict__ A, int n_nodes) {
    __shared__ float w[4 * HD];
    int t = threadIdx.x;
    w[t] = W0[t];
    __syncthreads();
    int n = blockIdx.x * 4 + (t >> 6);
    int c = t & 63;
    if (n >= n_nodes) return;
    float x0 = x[n * 4 + 0], x1 = x[n * 4 + 1], x2 = x[n * 4 + 2], x3 = x[n * 4 + 3];
    float v = x0 * w[c] + x1 * w[64 + c] + x2 * w[128 + c] + x3 * w[192 + c];
    A[((size_t)n << 6) + c] = __float2half(v * dinv[n]);
}

// edge-parallel aggregation: one block per 64-node group, fp32 LDS accumulator.
// 16-lane groups: each lane loads 8B (4 halves) of the 128B row -> one wave
// instruction covers 4 edges; 8-deep unroll -> 8 gathers in flight per group.
// Register-accumulate runs of equal dst (sorted), flush 4 LDS atomics on change.
__global__ __launch_bounds__(256) void k_aggr(const int* __restrict__ row_ptr,
        const unsigned* __restrict__ pedges, const __half* __restrict__ A,
        const float* __restrict__ dinv, const float* __restrict__ bias,
        float* __restrict__ B, float* __restrict__ stats, int n_nodes) {
    __shared__ float acc[64 * 65];
    __shared__ float ls[4][64], ls2[4][64];
    int t = threadIdx.x;
    for (int i = t; i < 64 * 65; i += 256) acc[i] = 0.f;
    int nodebase = blockIdx.x << 6;
    int nend = min(nodebase + 64, n_nodes);
    int ebeg = row_ptr[nodebase];
    int eend = row_ptr[nend];
    int nedges = eend - ebeg;
    __syncthreads();

    int wv = t >> 6, lane = t & 63;
    int sub = lane >> 4, ch = lane & 15;       // 16-lane group; ch*4 = channel base
    int s = wv * 4 + sub;                      // stream 0..15
    int sbeg = ebeg + (int)(((long long)nedges * s) >> 4);
    int send = ebeg + (int)(((long long)nedges * (s + 1)) >> 4);
    const uint2* A2 = (const uint2*)A;         // 16 uint2 per 64-half row

    float a0 = 0.f, a1 = 0.f, a2 = 0.f, a3 = 0.f;
    int cur = -1;

    #define FLUSH() if (cur >= 0) {                                            \
        int o_ = cur * 65 + (ch << 2);                                         \
        atomicAdd(&acc[o_ + 0], a0); atomicAdd(&acc[o_ + 1], a1);              \
        atomicAdd(&acc[o_ + 2], a2); atomicAdd(&acc[o_ + 3], a3); }

    #define PROC(P, U) {                                                       \
        int d_ = (int)((P) >> 17) & 63;                                        \
        if (d_ != cur) { FLUSH(); a0 = a1 = a2 = a3 = 0.f; cur = d_; }         \
        float2 f01_ = __half22float2(*(const __half2*)&(U).x);                 \
        float2 f23_ = __half22float2(*(const __half2*)&(U).y);                 \
        a0 += f01_.x; a1 += f01_.y; a2 += f23_.x; a3 += f23_.y; }

    int j = sbeg;
    for (; j + 8 <= send; j += 8) {
        unsigned p[8];
        uint2 u[8];
        #pragma unroll
        for (int k = 0; k < 8; ++k) p[k] = pedges[j + k];
        #pragma unroll
        for (int k = 0; k < 8; ++k)
            u[k] = A2[(((size_t)(p[k] & 0x1FFFFu)) << 4) + ch];
        #pragma unroll
        for (int k = 0; k < 8; ++k) PROC(p[k], u[k]);
    }
    for (; j < send; ++j) {
        unsigned p0 = pedges[j];
        uint2 u0 = A2[(((size_t)(p0 & 0x1FFFFu)) << 4) + ch];
        PROC(p0, u0);
    }
    FLUSH();
    #undef PROC
    #undef FLUSH
    __syncthreads();

    // finalize: wave wv handles rows wv, wv+4, ... ; lane = channel
    int c = lane;
    float st = 0.f, st2 = 0.f;
    for (int r = wv; r < 64; r += 4) {
        int node = nodebase + r;
        if (node < n_nodes) {
            float v = acc[r * 65 + c] + __half2float(A[((size_t)node << 6) + c]);
            v = dinv[node] * v + bias[c];
            B[((size_t)node << 6) + c] = v;
            st += v; st2 += v * v;
        }
    }
    ls[wv][c] = st; ls2[wv][c] = st2;
    __syncthreads();
    if (t < 64) {
        atomAddF(&stats[t], ls[0][t] + ls[1][t] + ls[2][t] + ls[3][t]);
        atomAddF(&stats[64 + t], ls2[0][t] + ls2[1][t] + ls2[2][t] + ls2[3][t]);
    }
}

// A(half) <- dinv[n] * (relu(bn(B)) @ W1)   (BN0+ReLU fused into row staging)
__global__ __launch_bounds__(256) void k_lin1(const float* __restrict__ B,
        const float* __restrict__ W, const float* __restrict__ dinv,
        const float* __restrict__ stats, const float* __restrict__ g,
        const float* __restrict__ be, __half* __restrict__ A, int n_nodes) {
    __shared__ float w[HD * HD];
    __shared__ float rows[4][HD];
    int t = threadIdx.x;
    for (int i = t; i < HD * HD; i += 256) w[i] = W[i];
    int wv = t >> 6, c = t & 63;
    float inv_n = 1.0f / (float)n_nodes;
    float mu = stats[c] * inv_n;
    float var = stats[64 + c] * inv_n - mu * mu;
    float sc = g[c] * rsqrtf(var + EPS);
    float sh = be[c] - mu * sc;
    int ngroups = (n_nodes + 3) >> 2;
    for (int gidx = blockIdx.x; gidx < ngroups; gidx += gridDim.x) {
        __syncthreads();
        int n = gidx * 4 + wv;
        float rv = (n < n_nodes) ? fmaxf(sc * B[((size_t)n << 6) + c] + sh, 0.f) : 0.f;
        rows[wv][c] = rv;
        __syncthreads();
        if (n < n_nodes) {
            float acc = 0.f;
            #pragma unroll
            for (int k = 0; k < HD; k++) acc = fmaf(rows[wv][k], w[k * 64 + c], acc);
            A[((size_t)n << 6) + c] = __float2half(acc * dinv[n]);
        }
    }
}

// fused MLP head, weight-coalesced: block = 32 nodes, wave = 8 nodes,
// lane = OUTPUT channel -> Wm0[k*64+j] is a coalesced 256B vector load;
// h[k] comes from LDS broadcast. m1: half-wave = 4 nodes x 32 channels.
// m2: shuffle reduce over the 32-lane half.
__global__ __launch_bounds__(256) void k_mlp(const float* __restrict__ B,
        const float* __restrict__ stats, const float* __restrict__ g,
        const float* __restrict__ be,
        const float* __restrict__ Wm0, const float* __restrict__ bm0,
        const float* __restrict__ Wm1, const float* __restrict__ bm1,
        const float* __restrict__ Wm2, const float* __restrict__ bm2,
        float* __restrict__ out, int n_nodes) {
    __shared__ float rows[32][66];      // 66: even stride, 8B-aligned float2
    __shared__ float scb[64], shb[64];
    int t = threadIdx.x;
    if (t < 64) {
        float inv_n = 1.0f / (float)n_nodes;
        float mu = stats[t] * inv_n;
        float var = stats[64 + t] * inv_n - mu * mu;
        float sc = g[t] * rsqrtf(var + EPS);
        scb[t] = sc;
        shb[t] = be[t] - mu * sc;
    }
    __syncthreads();
    int nbase = blockIdx.x * 32;
    #pragma unroll 8
    for (int i = 0; i < 8; ++i) {
        int idx = t + i * 256;          // 0..2047
        int r = idx >> 6, c = idx & 63;
        int nn = nbase + r;
        float v = (nn < n_nodes) ? B[((size_t)nn << 6) + c] : 0.f;
        rows[r][c] = fmaxf(scb[c] * v + shb[c], 0.f);
    }
    __syncthreads();

    int w = t >> 6, j = t & 63;
    int rb = w * 8;
    // ---- m0: 8 nodes/wave, lane = output channel ----
    float acc0[8];
    float b0j = bm0[j];
    #pragma unroll
    for (int i = 0; i < 8; ++i) acc0[i] = b0j;
    #pragma unroll 4
    for (int k = 0; k < 64; k += 2) {
        float wv0 = Wm0[k * 64 + j];
        float wv1 = Wm0[(k + 1) * 64 + j];
        #pragma unroll
        for (int i = 0; i < 8; ++i) {
            float2 hv = *(const float2*)&rows[rb + i][k];
            acc0[i] = fmaf(hv.x, wv0, acc0[i]);
            acc0[i] = fmaf(hv.y, wv1, acc0[i]);
        }
    }
    #pragma unroll
    for (int i = 0; i < 8; ++i) rows[rb + i][j] = fmaxf(acc0[i], 0.f);
    __syncthreads();
    // ---- m1: half-wave h -> nodes rb+h*4.., ch2 = output channel ----
    int h = j >> 5, ch2 = j & 31;
    int rb1 = rb + h * 4;
    float acc2[4];
    float b1j = bm1[ch2];
    #pragma unroll
    for (int i = 0; i < 4; ++i) acc2[i] = b1j;
    #pragma unroll 4
    for (int k = 0; k < 64; k += 2) {
        float wv0 = Wm1[k * 32 + ch2];
        float wv1 = Wm1[(k + 1) * 32 + ch2];
        #pragma unroll
        for (int i = 0; i < 4; ++i) {
            float2 hv = *(const float2*)&rows[rb1 + i][k];
            acc2[i] = fmaf(hv.x, wv0, acc2[i]);
            acc2[i] = fmaf(hv.y, wv1, acc2[i]);
        }
    }
    // ---- m2: per-node dot over 32 channels via shuffle reduce ----
    float wm2 = Wm2[ch2];
    float z[4];
    #pragma unroll
    for (int i = 0; i < 4; ++i) z[i] = fmaxf(acc2[i], 0.f) * wm2;
    #pragma unroll
    for (int d = 1; d < 32; d <<= 1) {
        #pragma unroll
        for (int i = 0; i < 4; ++i) z[i] += __shfl_xor(z[i], d, 64);
    }
    if (ch2 == 0) {
        float bb = bm2[0];
        #pragma unroll
        for (int i = 0; i < 4; ++i) {
            int nn = nbase + rb1 + i;
            if (nn < n_nodes)
                out[nn] = 1.0f / (1.0f + __expf(-(z[i] + bb)));
        }
    }
}

extern "C" void kernel_launch(void* const* d_in, const int* in_sizes, int n_in,
                              void* d_out, int out_size, void* d_ws, size_t ws_size,
                              hipStream_t stream) {
    const float* x   = (const float*)d_in[0];
    const int*   src = (const int*)d_in[1];
    const int*   dst = (const int*)d_in[2];
    const float* W0  = (const float*)d_in[3];
    const float* b0  = (const float*)d_in[4];
    const float* W1  = (const float*)d_in[5];
    const float* b1  = (const float*)d_in[6];
    const float* g0  = (const float*)d_in[7];
    const float* be0 = (const float*)d_in[8];
    const float* g1  = (const float*)d_in[9];
    const float* be1 = (const float*)d_in[10];
    const float* Wm0 = (const float*)d_in[11];
    const float* bm0 = (const float*)d_in[12];
    const float* Wm1 = (const float*)d_in[13];
    const float* bm1 = (const float*)d_in[14];
    const float* Wm2 = (const float*)d_in[15];
    const float* bm2 = (const float*)d_in[16];

    int n = in_sizes[0] / 4;
    int e = in_sizes[1];
    float* out = (float*)d_out;

    char* ws = (char*)d_ws;
    auto alignup = [](size_t v) { return (v + 255) & ~(size_t)255; };
    size_t o = 0;
    int*      bcnt    = (int*)(ws + o);      o += alignup(256 * 4);
    int*      boff    = (int*)(ws + o);      o += alignup(257 * 4);
    int*      gcur    = (int*)(ws + o);      o += alignup(256 * 4);
    float*    stats   = (float*)(ws + o);    o += alignup(256 * 4);
    int*      row_ptr = (int*)(ws + o);      o += alignup((size_t)(n + 1) * 4);
    float*    dinv    = (float*)(ws + o);    o += alignup((size_t)n * 4);
    unsigned* bedges  = (unsigned*)(ws + o); o += alignup((size_t)e * 4);
    unsigned* csr     = (unsigned*)(ws + o); o += alignup((size_t)e * 4);
    __half*   A       = (__half*)(ws + o);   o += alignup((size_t)n * 64 * 2);
    float*    B       = (float*)(ws + o);

    int nb     = (n + BSZ - 1) >> BSH;        // 196 buckets for n=100k (requires n<=131072)
    int gN4    = (n + 3) / 4;
    int ntiles = (e + T1 - 1) / T1;
    int gMLP   = (n + 31) / 32;
    int gAGG   = (n + 63) / 64;               // one block per 64-node group

    (void)hipMemsetAsync(bcnt, 0, 256 * 4, stream);
    (void)hipMemsetAsync(stats, 0, 256 * 4, stream);

    // ---- CSR build (bucketed, once, reused by both layers) ----
    k_bhist<<<512, 256, 0, stream>>>(dst, bcnt, e);
    k_bscan<<<1, 256, 0, stream>>>(bcnt, boff, gcur, row_ptr, nb, n, e);
    k_bucket<<<ntiles, 256, 0, stream>>>(src, dst, gcur, bedges, e);
    k_build<<<nb, 256, 0, stream>>>(bedges, boff, row_ptr, csr, dinv, n);

    // ---- layer 1 ----
    k_lin0<<<gN4, 256, 0, stream>>>(x, W0, dinv, A, n);
    k_aggr<<<gAGG, 256, 0, stream>>>(row_ptr, csr, A, dinv, b0, B, stats, n);

    // ---- layer 2 (BN0+ReLU fused into lin1) ----
    k_lin1<<<2048, 256, 0, stream>>>(B, W1, dinv, stats, g0, be0, A, n);
    k_aggr<<<gAGG, 256, 0, stream>>>(row_ptr, csr, A, dinv, b1, B, stats + 128, n);

    // ---- MLP head (BN1+ReLU fused) ----
    k_mlp<<<gMLP, 256, 0, stream>>>(B, stats + 128, g1, be1,
                                    Wm0, bm0, Wm1, bm1, Wm2, bm2, out, n);
}

// Round 13
// 369.543 us; speedup vs baseline: 1.5898x; 1.0705x over previous
//
#include <hip/hip_runtime.h>
#include <hip/hip_fp16.h>
#include <math.h>

#define HD 64
#define EPS 1e-5f
#define BSH 9                   // bucket shift: 512 nodes per bucket
#define BSZ 512
#define T1 16384                // edges per tile in k_bucket
#define BCAP 20480              // fixed bucket capacity (mean 16326, sigma 127 -> 32-sigma slack)
// packing: n <= 131072 (2^17) required: packed = (local_dst<<17) | src

__device__ __forceinline__ float atomAddF(float* p, float v) {
    return unsafeAtomicAdd(p, v);   // native global_atomic_add_f32 on gfx950
}

// ---------- CSR build (bucketed counting sort, fixed-capacity reservation) ----------

// init per-bucket global cursors to sparse bucket bases
__global__ void k_ginit(int* __restrict__ gcur) {
    int t = threadIdx.x;
    gcur[t] = t * BCAP;
}

// pass 1: scatter packed edges into per-bucket sparse regions (no pre-histogram)
__global__ __launch_bounds__(256) void k_bucket(const int* __restrict__ src,
        const int* __restrict__ dst, int* __restrict__ gcur,
        unsigned* __restrict__ bedges, int e) {
    __shared__ int hist[256];
    __shared__ int base[256];
    int t = threadIdx.x;
    for (int tile = blockIdx.x * T1; tile < e; tile += gridDim.x * T1) {
        int lim = min(e - tile, T1);
        hist[t] = 0;
        __syncthreads();
        for (int j = t; j < lim; j += 256)
            atomicAdd(&hist[dst[tile + j] >> BSH], 1);
        __syncthreads();
        int h = hist[t];
        int mybase = (h > 0) ? atomicAdd(&gcur[t], h) : 0;
        __syncthreads();
        hist[t] = 0;                 // reuse as local cursor
        base[t] = mybase;
        __syncthreads();
        for (int j = t; j < lim; j += 256) {
            int d = dst[tile + j], s = src[tile + j];
            int bk = d >> BSH;
            int loc = atomicAdd(&hist[bk], 1);
            bedges[base[bk] + loc] = ((unsigned)(d & (BSZ - 1)) << 17) | (unsigned)s;
        }
        __syncthreads();
    }
}

// scan bucket counts (derived from final gcur) -> compact offsets boff
__global__ __launch_bounds__(256) void k_bscan(const int* __restrict__ gcur,
        int* __restrict__ boff, int* __restrict__ row_ptr, int nb, int n, int e) {
    __shared__ int sc[256];
    int t = threadIdx.x;
    int v = (t < nb) ? (gcur[t] - t * BCAP) : 0;
    sc[t] = v;
    __syncthreads();
    int acc = v;
    for (int off = 1; off < 256; off <<= 1) {
        int x = (t >= off) ? sc[t - off] : 0;
        __syncthreads();
        acc += x;
        sc[t] = acc;
        __syncthreads();
    }
    boff[t] = acc - v;               // thread nb writes boff[nb] = e
    if (t == 0) row_ptr[n] = e;
}

// pass 2: one block per bucket -> row_ptr, dinv, csr (compact, sorted by dst).
// reads bedges from sparse region [b*BCAP, b*BCAP+cnt)
__global__ __launch_bounds__(256) void k_build(const unsigned* __restrict__ bedges,
        const int* __restrict__ boff, int* __restrict__ row_ptr,
        unsigned* __restrict__ csr, float* __restrict__ dinv, int n) {
    __shared__ int hist[BSZ];
    __shared__ int cur[BSZ];
    __shared__ int sc[256];
    int b = blockIdx.x, t = threadIdx.x;
    int nodebase = b << BSH;
    int cbase = boff[b];
    int cnt = boff[b + 1] - cbase;
    const unsigned* bed = bedges + (size_t)b * BCAP;
    hist[t] = 0; hist[t + 256] = 0;
    __syncthreads();
    for (int j = t; j < cnt; j += 256)
        atomicAdd(&hist[bed[j] >> 17], 1);
    __syncthreads();
    int a0 = hist[2 * t], a1 = hist[2 * t + 1];
    int psum = a0 + a1;
    sc[t] = psum;
    __syncthreads();
    int acc = psum;
    for (int off = 1; off < 256; off <<= 1) {
        int x = (t >= off) ? sc[t - off] : 0;
        __syncthreads();
        acc += x;
        sc[t] = acc;
        __syncthreads();
    }
    int excl = acc - psum;           // exclusive over node pairs
    int e0 = cbase + excl, e1 = cbase + excl + a0;
    cur[2 * t] = e0;
    cur[2 * t + 1] = e1;
    int n0 = nodebase + 2 * t, n1 = nodebase + 2 * t + 1;
    if (n0 < n) { row_ptr[n0] = e0; dinv[n0] = rsqrtf((float)(a0 + 1)); }
    if (n1 < n) { row_ptr[n1] = e1; dinv[n1] = rsqrtf((float)(a1 + 1)); }
    __syncthreads();
    for (int j = t; j < cnt; j += 256) {
        unsigned p = bed[j];
        int pos = atomicAdd(&cur[p >> 17], 1);
        csr[pos] = p;
    }
}

// ---------- layer compute ----------
// A: fp16, linear rows A[n*64+c] (128B per row)

// A[n][c] = half( dinv[n] * sum_k x[n][k]*W0[k][c] )
__global__ __launch_bounds__(256) void k_lin0(const float* __restrict__ x,
        const float* __restrict__ W0, const float* __restrict__ dinv,
        __half* __restrict__ A, int n_nodes) {
    __shared__ float w[4 * HD];
    int t = threadIdx.x;
    w[t] = W0[t];
    __syncthreads();
    int n = blockIdx.x * 4 + (t >> 6);
    int c = t & 63;
    if (n >= n_nodes) return;
    float x0 = x[n * 4 + 0], x1 = x[n * 4 + 1], x2 = x[n * 4 + 2], x3 = x[n * 4 + 3];
    float v = x0 * w[c] + x1 * w[64 + c] + x2 * w[128 + c] + x3 * w[192 + c];
    A[((size_t)n << 6) + c] = __float2half(v * dinv[n]);
}

// edge-parallel aggregation: one block per 64-node group, fp32 LDS accumulator.
// 16-lane groups: each lane loads 8B (4 halves) of the 128B row -> one wave
// instruction covers 4 edges; 16-deep unroll -> 16 gathers in flight per group.
// Register-accumulate runs of equal dst (sorted), flush 4 LDS atomics on change.
__global__ __launch_bounds__(256) void k_aggr(const int* __restrict__ row_ptr,
        const unsigned* __restrict__ pedges, const __half* __restrict__ A,
        const float* __restrict__ dinv, const float* __restrict__ bias,
        float* __restrict__ B, float* __restrict__ stats, int n_nodes) {
    __shared__ float acc[64 * 65];
    __shared__ float ls[4][64], ls2[4][64];
    int t = threadIdx.x;
    for (int i = t; i < 64 * 65; i += 256) acc[i] = 0.f;
    int nodebase = blockIdx.x << 6;
    int nend = min(nodebase + 64, n_nodes);
    int ebeg = row_ptr[nodebase];
    int eend = row_ptr[nend];
    int nedges = eend - ebeg;
    __syncthreads();

    int wv = t >> 6, lane = t & 63;
    int sub = lane >> 4, ch = lane & 15;       // 16-lane group; ch*4 = channel base
    int s = wv * 4 + sub;                      // stream 0..15
    int sbeg = ebeg + (int)(((long long)nedges * s) >> 4);
    int send = ebeg + (int)(((long long)nedges * (s + 1)) >> 4);
    const uint2* A2 = (const uint2*)A;         // 16 uint2 per 64-half row

    float a0 = 0.f, a1 = 0.f, a2 = 0.f, a3 = 0.f;
    int cur = -1;

    #define FLUSH() if (cur >= 0) {                                            \
        int o_ = cur * 65 + (ch << 2);                                         \
        atomicAdd(&acc[o_ + 0], a0); atomicAdd(&acc[o_ + 1], a1);              \
        atomicAdd(&acc[o_ + 2], a2); atomicAdd(&acc[o_ + 3], a3); }

    #define PROC(P, U) {                                                       \
        int d_ = (int)((P) >> 17) & 63;                                        \
        if (d_ != cur) { FLUSH(); a0 = a1 = a2 = a3 = 0.f; cur = d_; }         \
        float2 f01_ = __half22float2(*(const __half2*)&(U).x);                 \
        float2 f23_ = __half22float2(*(const __half2*)&(U).y);                 \
        a0 += f01_.x; a1 += f01_.y; a2 += f23_.x; a3 += f23_.y; }

    int j = sbeg;
    for (; j + 16 <= send; j += 16) {
        unsigned p[16];
        uint2 u[16];
        #pragma unroll
        for (int k = 0; k < 16; ++k) p[k] = pedges[j + k];
        #pragma unroll
        for (int k = 0; k < 16; ++k)
            u[k] = A2[(((size_t)(p[k] & 0x1FFFFu)) << 4) + ch];
        #pragma unroll
        for (int k = 0; k < 16; ++k) PROC(p[k], u[k]);
    }
    for (; j < send; ++j) {
        unsigned p0 = pedges[j];
        uint2 u0 = A2[(((size_t)(p0 & 0x1FFFFu)) << 4) + ch];
        PROC(p0, u0);
    }
    FLUSH();
    #undef PROC
    #undef FLUSH
    __syncthreads();

    // finalize: wave wv handles rows wv, wv+4, ... ; lane = channel
    int c = lane;
    float st = 0.f, st2 = 0.f;
    for (int r = wv; r < 64; r += 4) {
        int node = nodebase + r;
        if (node < n_nodes) {
            float v = acc[r * 65 + c] + __half2float(A[((size_t)node << 6) + c]);
            v = dinv[node] * v + bias[c];
            B[((size_t)node << 6) + c] = v;
            st += v; st2 += v * v;
        }
    }
    ls[wv][c] = st; ls2[wv][c] = st2;
    __syncthreads();
    if (t < 64) {
        atomAddF(&stats[t], ls[0][t] + ls[1][t] + ls[2][t] + ls[3][t]);
        atomAddF(&stats[64 + t], ls2[0][t] + ls2[1][t] + ls2[2][t] + ls2[3][t]);
    }
}

// A(half) <- dinv[n] * (relu(bn(B)) @ W1)   (BN0+ReLU fused into row staging)
__global__ __launch_bounds__(256) void k_lin1(const float* __restrict__ B,
        const float* __restrict__ W, const float* __restrict__ dinv,
        const float* __restrict__ stats, const float* __restrict__ g,
        const float* __restrict__ be, __half* __restrict__ A, int n_nodes) {
    __shared__ float w[HD * HD];
    __shared__ float rows[4][HD];
    int t = threadIdx.x;
    for (int i = t; i < HD * HD; i += 256) w[i] = W[i];
    int wv = t >> 6, c = t & 63;
    float inv_n = 1.0f / (float)n_nodes;
    float mu = stats[c] * inv_n;
    float var = stats[64 + c] * inv_n - mu * mu;
    float sc = g[c] * rsqrtf(var + EPS);
    float sh = be[c] - mu * sc;
    int ngroups = (n_nodes + 3) >> 2;
    for (int gidx = blockIdx.x; gidx < ngroups; gidx += gridDim.x) {
        __syncthreads();
        int n = gidx * 4 + wv;
        float rv = (n < n_nodes) ? fmaxf(sc * B[((size_t)n << 6) + c] + sh, 0.f) : 0.f;
        rows[wv][c] = rv;
        __syncthreads();
        if (n < n_nodes) {
            float acc = 0.f;
            #pragma unroll
            for (int k = 0; k < HD; k++) acc = fmaf(rows[wv][k], w[k * 64 + c], acc);
            A[((size_t)n << 6) + c] = __float2half(acc * dinv[n]);
        }
    }
}

// fused MLP head, weight-coalesced: block = 32 nodes, wave = 8 nodes,
// lane = OUTPUT channel -> Wm0[k*64+j] is a coalesced 256B vector load;
// h[k] comes from LDS broadcast. m1: half-wave = 4 nodes x 32 channels.
// m2: shuffle reduce over the 32-lane half.
__global__ __launch_bounds__(256) void k_mlp(const float* __restrict__ B,
        const float* __restrict__ stats, const float* __restrict__ g,
        const float* __restrict__ be,
        const float* __restrict__ Wm0, const float* __restrict__ bm0,
        const float* __restrict__ Wm1, const float* __restrict__ bm1,
        const float* __restrict__ Wm2, const float* __restrict__ bm2,
        float* __restrict__ out, int n_nodes) {
    __shared__ float rows[32][66];      // 66: even stride, 8B-aligned float2
    __shared__ float scb[64], shb[64];
    int t = threadIdx.x;
    if (t < 64) {
        float inv_n = 1.0f / (float)n_nodes;
        float mu = stats[t] * inv_n;
        float var = stats[64 + t] * inv_n - mu * mu;
        float sc = g[t] * rsqrtf(var + EPS);
        scb[t] = sc;
        shb[t] = be[t] - mu * sc;
    }
    __syncthreads();
    int nbase = blockIdx.x * 32;
    #pragma unroll 8
    for (int i = 0; i < 8; ++i) {
        int idx = t + i * 256;          // 0..2047
        int r = idx >> 6, c = idx & 63;
        int nn = nbase + r;
        float v = (nn < n_nodes) ? B[((size_t)nn << 6) + c] : 0.f;
        rows[r][c] = fmaxf(scb[c] * v + shb[c], 0.f);
    }
    __syncthreads();

    int w = t >> 6, j = t & 63;
    int rb = w * 8;
    // ---- m0: 8 nodes/wave, lane = output channel ----
    float acc0[8];
    float b0j = bm0[j];
    #pragma unroll
    for (int i = 0; i < 8; ++i) acc0[i] = b0j;
    #pragma unroll 4
    for (int k = 0; k < 64; k += 2) {
        float wv0 = Wm0[k * 64 + j];
        float wv1 = Wm0[(k + 1) * 64 + j];
        #pragma unroll
        for (int i = 0; i < 8; ++i) {
            float2 hv = *(const float2*)&rows[rb + i][k];
            acc0[i] = fmaf(hv.x, wv0, acc0[i]);
            acc0[i] = fmaf(hv.y, wv1, acc0[i]);
        }
    }
    #pragma unroll
    for (int i = 0; i < 8; ++i) rows[rb + i][j] = fmaxf(acc0[i], 0.f);
    __syncthreads();
    // ---- m1: half-wave h -> nodes rb+h*4.., ch2 = output channel ----
    int h = j >> 5, ch2 = j & 31;
    int rb1 = rb + h * 4;
    float acc2[4];
    float b1j = bm1[ch2];
    #pragma unroll
    for (int i = 0; i < 4; ++i) acc2[i] = b1j;
    #pragma unroll 4
    for (int k = 0; k < 64; k += 2) {
        float wv0 = Wm1[k * 32 + ch2];
        float wv1 = Wm1[(k + 1) * 32 + ch2];
        #pragma unroll
        for (int i = 0; i < 4; ++i) {
            float2 hv = *(const float2*)&rows[rb1 + i][k];
            acc2[i] = fmaf(hv.x, wv0, acc2[i]);
            acc2[i] = fmaf(hv.y, wv1, acc2[i]);
        }
    }
    // ---- m2: per-node dot over 32 channels via shuffle reduce ----
    float wm2 = Wm2[ch2];
    float z[4];
    #pragma unroll
    for (int i = 0; i < 4; ++i) z[i] = fmaxf(acc2[i], 0.f) * wm2;
    #pragma unroll
    for (int d = 1; d < 32; d <<= 1) {
        #pragma unroll
        for (int i = 0; i < 4; ++i) z[i] += __shfl_xor(z[i], d, 64);
    }
    if (ch2 == 0) {
        float bb = bm2[0];
        #pragma unroll
        for (int i = 0; i < 4; ++i) {
            int nn = nbase + rb1 + i;
            if (nn < n_nodes)
                out[nn] = 1.0f / (1.0f + __expf(-(z[i] + bb)));
        }
    }
}

extern "C" void kernel_launch(void* const* d_in, const int* in_sizes, int n_in,
                              void* d_out, int out_size, void* d_ws, size_t ws_size,
                              hipStream_t stream) {
    const float* x   = (const float*)d_in[0];
    const int*   src = (const int*)d_in[1];
    const int*   dst = (const int*)d_in[2];
    const float* W0  = (const float*)d_in[3];
    const float* b0  = (const float*)d_in[4];
    const float* W1  = (const float*)d_in[5];
    const float* b1  = (const float*)d_in[6];
    const float* g0  = (const float*)d_in[7];
    const float* be0 = (const float*)d_in[8];
    const float* g1  = (const float*)d_in[9];
    const float* be1 = (const float*)d_in[10];
    const float* Wm0 = (const float*)d_in[11];
    const float* bm0 = (const float*)d_in[12];
    const float* Wm1 = (const float*)d_in[13];
    const float* bm1 = (const float*)d_in[14];
    const float* Wm2 = (const float*)d_in[15];
    const float* bm2 = (const float*)d_in[16];

    int n = in_sizes[0] / 4;
    int e = in_sizes[1];
    float* out = (float*)d_out;

    int nb = (n + BSZ - 1) >> BSH;            // 196 buckets for n=100k

    char* ws = (char*)d_ws;
    auto alignup = [](size_t v) { return (v + 255) & ~(size_t)255; };
    size_t o = 0;
    int*      boff    = (int*)(ws + o);      o += alignup(257 * 4);
    int*      gcur    = (int*)(ws + o);      o += alignup(256 * 4);
    float*    stats   = (float*)(ws + o);    o += alignup(256 * 4);
    int*      row_ptr = (int*)(ws + o);      o += alignup((size_t)(n + 1) * 4);
    float*    dinv    = (float*)(ws + o);    o += alignup((size_t)n * 4);
    unsigned* bedges  = (unsigned*)(ws + o); o += alignup((size_t)nb * BCAP * 4);
    unsigned* csr     = (unsigned*)(ws + o); o += alignup((size_t)e * 4);
    __half*   A       = (__half*)(ws + o);   o += alignup((size_t)n * 64 * 2);
    float*    B       = (float*)(ws + o);

    int gN4    = (n + 3) / 4;
    int ntiles = (e + T1 - 1) / T1;
    int gMLP   = (n + 31) / 32;
    int gAGG   = (n + 63) / 64;               // one block per 64-node group

    (void)hipMemsetAsync(stats, 0, 256 * 4, stream);

    // ---- CSR build (bucketed, fixed-capacity reservation; once, reused) ----
    k_ginit<<<1, 256, 0, stream>>>(gcur);
    k_bucket<<<ntiles, 256, 0, stream>>>(src, dst, gcur, bedges, e);
    k_bscan<<<1, 256, 0, stream>>>(gcur, boff, row_ptr, nb, n, e);
    k_build<<<nb, 256, 0, stream>>>(bedges, boff, row_ptr, csr, dinv, n);

    // ---- layer 1 ----
    k_lin0<<<gN4, 256, 0, stream>>>(x, W0, dinv, A, n);
    k_aggr<<<gAGG, 256, 0, stream>>>(row_ptr, csr, A, dinv, b0, B, stats, n);

    // ---- layer 2 (BN0+ReLU fused into lin1) ----
    k_lin1<<<2048, 256, 0, stream>>>(B, W1, dinv, stats, g0, be0, A, n);
    k_aggr<<<gAGG, 256, 0, stream>>>(row_ptr, csr, A, dinv, b1, B, stats + 128, n);

    // ---- MLP head (BN1+ReLU fused) ----
    k_mlp<<<gMLP, 256, 0, stream>>>(B, stats + 128, g1, be1,
                                    Wm0, bm0, Wm1, bm1, Wm2, bm2, out, n);
}

// Round 14
// 334.937 us; speedup vs baseline: 1.7541x; 1.1033x over previous
//
#include <hip/hip_runtime.h>
#include <hip/hip_fp16.h>
#include <math.h>

#define HD 64
#define EPS 1e-5f
#define BSH 8                   // bucket shift: 256 nodes per bucket
#define BSZ 256
#define T1 4096                 // edges per tile in k_bucket (16 per thread, in regs)
#define BCAP 10240              // fixed bucket capacity (mean 8192, sigma ~90 -> 22-sigma slack)
// packing: n <= 131072 (2^17) required: packed = (local_dst<<17) | src

__device__ __forceinline__ float atomAddF(float* p, float v) {
    return unsafeAtomicAdd(p, v);   // native global_atomic_add_f32 on gfx950
}

// ---------- CSR build (bucketed counting sort, fixed-capacity reservation) ----------

// init per-bucket global cursors to sparse bucket bases
__global__ __launch_bounds__(512) void k_ginit(int* __restrict__ gcur) {
    int t = threadIdx.x;
    gcur[t] = t * BCAP;
}

// pass 1: one-read bucketing. Each thread keeps its 16 edges in registers
// (int4 loads), LDS-hists, block reserves per-bucket space, scatters from regs.
__global__ __launch_bounds__(256) void k_bucket(const int* __restrict__ src,
        const int* __restrict__ dst, int* __restrict__ gcur,
        unsigned* __restrict__ bedges, int e, int nbuck) {
    __shared__ int hist[512];
    __shared__ int base[512];
    int t = threadIdx.x;
    int tile = blockIdx.x * T1;
    int lim = min(e - tile, T1);
    hist[t] = 0; hist[t + 256] = 0;
    __syncthreads();
    int d_[16], s_[16];
    bool full = (lim == T1);
    if (full) {
        const int4* d4 = (const int4*)(dst + tile);
        const int4* s4 = (const int4*)(src + tile);
        #pragma unroll
        for (int j = 0; j < 4; ++j) {
            int4 dv = d4[j * 256 + t];
            int4 sv = s4[j * 256 + t];
            d_[4 * j + 0] = dv.x; d_[4 * j + 1] = dv.y;
            d_[4 * j + 2] = dv.z; d_[4 * j + 3] = dv.w;
            s_[4 * j + 0] = sv.x; s_[4 * j + 1] = sv.y;
            s_[4 * j + 2] = sv.z; s_[4 * j + 3] = sv.w;
        }
        #pragma unroll
        for (int j = 0; j < 16; ++j) atomicAdd(&hist[d_[j] >> BSH], 1);
    } else {
        for (int j = t; j < lim; j += 256)
            atomicAdd(&hist[dst[tile + j] >> BSH], 1);
    }
    __syncthreads();
    for (int b = t; b < nbuck; b += 256) {
        int h = hist[b];
        base[b] = (h > 0) ? atomicAdd(&gcur[b], h) : 0;
        hist[b] = 0;                 // reuse as local cursor
    }
    __syncthreads();
    if (full) {
        #pragma unroll
        for (int j = 0; j < 16; ++j) {
            int bk = d_[j] >> BSH;
            int loc = atomicAdd(&hist[bk], 1);
            bedges[base[bk] + loc] =
                ((unsigned)(d_[j] & (BSZ - 1)) << 17) | (unsigned)s_[j];
        }
    } else {
        for (int j = t; j < lim; j += 256) {
            int d = dst[tile + j], s = src[tile + j];
            int bk = d >> BSH;
            int loc = atomicAdd(&hist[bk], 1);
            bedges[base[bk] + loc] = ((unsigned)(d & (BSZ - 1)) << 17) | (unsigned)s;
        }
    }
}

// scan bucket counts (derived from final gcur) -> compact offsets boff
__global__ __launch_bounds__(512) void k_bscan(const int* __restrict__ gcur,
        int* __restrict__ boff, int* __restrict__ row_ptr, int nb, int n, int e) {
    __shared__ int sc[512];
    int t = threadIdx.x;
    int v = (t < nb) ? (gcur[t] - t * BCAP) : 0;
    sc[t] = v;
    __syncthreads();
    int acc = v;
    for (int off = 1; off < 512; off <<= 1) {
        int x = (t >= off) ? sc[t - off] : 0;
        __syncthreads();
        acc += x;
        sc[t] = acc;
        __syncthreads();
    }
    boff[t] = acc - v;               // boff[nb] = e
    if (t == 0) row_ptr[n] = e;
}

// pass 2: one block per 256-node bucket -> row_ptr, dinv, csr (compact).
// uint4-vectorized passes over the sparse bucket region.
__global__ __launch_bounds__(256) void k_build(const unsigned* __restrict__ bedges,
        const int* __restrict__ boff, int* __restrict__ row_ptr,
        unsigned* __restrict__ csr, float* __restrict__ dinv, int n) {
    __shared__ int hist[BSZ];
    __shared__ int cur[BSZ];
    __shared__ int sc[256];
    int b = blockIdx.x, t = threadIdx.x;
    int nodebase = b << BSH;
    int cbase = boff[b];
    int cnt = boff[b + 1] - cbase;
    const unsigned* bed = bedges + (size_t)b * BCAP;
    hist[t] = 0;
    __syncthreads();
    int cnt4 = cnt & ~3;
    for (int jj = t * 4; jj < cnt4; jj += 1024) {
        uint4 p = *(const uint4*)(bed + jj);
        atomicAdd(&hist[p.x >> 17], 1); atomicAdd(&hist[p.y >> 17], 1);
        atomicAdd(&hist[p.z >> 17], 1); atomicAdd(&hist[p.w >> 17], 1);
    }
    for (int jj = cnt4 + t; jj < cnt; jj += 256)
        atomicAdd(&hist[bed[jj] >> 17], 1);
    __syncthreads();
    int a = hist[t];
    sc[t] = a;
    __syncthreads();
    int acc = a;
    for (int off = 1; off < 256; off <<= 1) {
        int x = (t >= off) ? sc[t - off] : 0;
        __syncthreads();
        acc += x;
        sc[t] = acc;
        __syncthreads();
    }
    int e0 = cbase + acc - a;        // exclusive
    cur[t] = e0;
    int node = nodebase + t;
    if (node < n) { row_ptr[node] = e0; dinv[node] = rsqrtf((float)(a + 1)); }
    __syncthreads();
    for (int jj = t * 4; jj < cnt4; jj += 1024) {
        uint4 p = *(const uint4*)(bed + jj);
        int p0 = atomicAdd(&cur[p.x >> 17], 1); csr[p0] = p.x;
        int p1 = atomicAdd(&cur[p.y >> 17], 1); csr[p1] = p.y;
        int p2 = atomicAdd(&cur[p.z >> 17], 1); csr[p2] = p.z;
        int p3 = atomicAdd(&cur[p.w >> 17], 1); csr[p3] = p.w;
    }
    for (int jj = cnt4 + t; jj < cnt; jj += 256) {
        unsigned p = bed[jj];
        int pos = atomicAdd(&cur[p >> 17], 1);
        csr[pos] = p;
    }
}

// ---------- layer compute ----------
// A: fp16, linear rows A[n*64+c] (128B per row)

// A[n][c] = half( dinv[n] * sum_k x[n][k]*W0[k][c] )
__global__ __launch_bounds__(256) void k_lin0(const float* __restrict__ x,
        const float* __restrict__ W0, const float* __restrict__ dinv,
        __half* __restrict__ A, int n_nodes) {
    __shared__ float w[4 * HD];
    int t = threadIdx.x;
    w[t] = W0[t];
    __syncthreads();
    int n = blockIdx.x * 4 + (t >> 6);
    int c = t & 63;
    if (n >= n_nodes) return;
    float x0 = x[n * 4 + 0], x1 = x[n * 4 + 1], x2 = x[n * 4 + 2], x3 = x[n * 4 + 3];
    float v = x0 * w[c] + x1 * w[64 + c] + x2 * w[128 + c] + x3 * w[192 + c];
    A[((size_t)n << 6) + c] = __float2half(v * dinv[n]);
}

// edge-parallel aggregation: one block per 64-node group, fp32 LDS accumulator.
// 16-lane groups: each lane loads 8B (4 halves) of the 128B row -> one wave
// instruction covers 4 edges; 16-deep unroll -> 16 gathers in flight per group.
// Register-accumulate runs of equal dst (sorted), flush 4 LDS atomics on change.
__global__ __launch_bounds__(256) void k_aggr(const int* __restrict__ row_ptr,
        const unsigned* __restrict__ pedges, const __half* __restrict__ A,
        const float* __restrict__ dinv, const float* __restrict__ bias,
        float* __restrict__ B, float* __restrict__ stats, int n_nodes) {
    __shared__ float acc[64 * 65];
    __shared__ float ls[4][64], ls2[4][64];
    int t = threadIdx.x;
    for (int i = t; i < 64 * 65; i += 256) acc[i] = 0.f;
    int nodebase = blockIdx.x << 6;
    int nend = min(nodebase + 64, n_nodes);
    int ebeg = row_ptr[nodebase];
    int eend = row_ptr[nend];
    int nedges = eend - ebeg;
    __syncthreads();

    int wv = t >> 6, lane = t & 63;
    int sub = lane >> 4, ch = lane & 15;       // 16-lane group; ch*4 = channel base
    int s = wv * 4 + sub;                      // stream 0..15
    int sbeg = ebeg + (int)(((long long)nedges * s) >> 4);
    int send = ebeg + (int)(((long long)nedges * (s + 1)) >> 4);
    const uint2* A2 = (const uint2*)A;         // 16 uint2 per 64-half row

    float a0 = 0.f, a1 = 0.f, a2 = 0.f, a3 = 0.f;
    int cur = -1;

    #define FLUSH() if (cur >= 0) {                                            \
        int o_ = cur * 65 + (ch << 2);                                         \
        atomicAdd(&acc[o_ + 0], a0); atomicAdd(&acc[o_ + 1], a1);              \
        atomicAdd(&acc[o_ + 2], a2); atomicAdd(&acc[o_ + 3], a3); }

    #define PROC(P, U) {                                                       \
        int d_ = (int)((P) >> 17) & 63;                                        \
        if (d_ != cur) { FLUSH(); a0 = a1 = a2 = a3 = 0.f; cur = d_; }         \
        float2 f01_ = __half22float2(*(const __half2*)&(U).x);                 \
        float2 f23_ = __half22float2(*(const __half2*)&(U).y);                 \
        a0 += f01_.x; a1 += f01_.y; a2 += f23_.x; a3 += f23_.y; }

    int j = sbeg;
    for (; j + 16 <= send; j += 16) {
        unsigned p[16];
        uint2 u[16];
        #pragma unroll
        for (int k = 0; k < 16; ++k) p[k] = pedges[j + k];
        #pragma unroll
        for (int k = 0; k < 16; ++k)
            u[k] = A2[(((size_t)(p[k] & 0x1FFFFu)) << 4) + ch];
        #pragma unroll
        for (int k = 0; k < 16; ++k) PROC(p[k], u[k]);
    }
    for (; j < send; ++j) {
        unsigned p0 = pedges[j];
        uint2 u0 = A2[(((size_t)(p0 & 0x1FFFFu)) << 4) + ch];
        PROC(p0, u0);
    }
    FLUSH();
    #undef PROC
    #undef FLUSH
    __syncthreads();

    // finalize: wave wv handles rows wv, wv+4, ... ; lane = channel
    int c = lane;
    float st = 0.f, st2 = 0.f;
    for (int r = wv; r < 64; r += 4) {
        int node = nodebase + r;
        if (node < n_nodes) {
            float v = acc[r * 65 + c] + __half2float(A[((size_t)node << 6) + c]);
            v = dinv[node] * v + bias[c];
            B[((size_t)node << 6) + c] = v;
            st += v; st2 += v * v;
        }
    }
    ls[wv][c] = st; ls2[wv][c] = st2;
    __syncthreads();
    if (t < 64) {
        atomAddF(&stats[t], ls[0][t] + ls[1][t] + ls[2][t] + ls[3][t]);
        atomAddF(&stats[64 + t], ls2[0][t] + ls2[1][t] + ls2[2][t] + ls2[3][t]);
    }
}

// A(half) <- dinv[n] * (relu(bn(B)) @ W1)   (BN0+ReLU fused into row staging)
__global__ __launch_bounds__(256) void k_lin1(const float* __restrict__ B,
        const float* __restrict__ W, const float* __restrict__ dinv,
        const float* __restrict__ stats, const float* __restrict__ g,
        const float* __restrict__ be, __half* __restrict__ A, int n_nodes) {
    __shared__ float w[HD * HD];
    __shared__ float rows[4][HD];
    int t = threadIdx.x;
    for (int i = t; i < HD * HD; i += 256) w[i] = W[i];
    int wv = t >> 6, c = t & 63;
    float inv_n = 1.0f / (float)n_nodes;
    float mu = stats[c] * inv_n;
    float var = stats[64 + c] * inv_n - mu * mu;
    float sc = g[c] * rsqrtf(var + EPS);
    float sh = be[c] - mu * sc;
    int ngroups = (n_nodes + 3) >> 2;
    for (int gidx = blockIdx.x; gidx < ngroups; gidx += gridDim.x) {
        __syncthreads();
        int n = gidx * 4 + wv;
        float rv = (n < n_nodes) ? fmaxf(sc * B[((size_t)n << 6) + c] + sh, 0.f) : 0.f;
        rows[wv][c] = rv;
        __syncthreads();
        if (n < n_nodes) {
            float acc = 0.f;
            #pragma unroll
            for (int k = 0; k < HD; k++) acc = fmaf(rows[wv][k], w[k * 64 + c], acc);
            A[((size_t)n << 6) + c] = __float2half(acc * dinv[n]);
        }
    }
}

// fused MLP head, weight-coalesced: block = 32 nodes, wave = 8 nodes,
// lane = OUTPUT channel -> Wm0[k*64+j] is a coalesced 256B vector load;
// h[k] comes from LDS broadcast. m1: half-wave = 4 nodes x 32 channels.
// m2: shuffle reduce over the 32-lane half.
__global__ __launch_bounds__(256) void k_mlp(const float* __restrict__ B,
        const float* __restrict__ stats, const float* __restrict__ g,
        const float* __restrict__ be,
        const float* __restrict__ Wm0, const float* __restrict__ bm0,
        const float* __restrict__ Wm1, const float* __restrict__ bm1,
        const float* __restrict__ Wm2, const float* __restrict__ bm2,
        float* __restrict__ out, int n_nodes) {
    __shared__ float rows[32][66];      // 66: even stride, 8B-aligned float2
    __shared__ float scb[64], shb[64];
    int t = threadIdx.x;
    if (t < 64) {
        float inv_n = 1.0f / (float)n_nodes;
        float mu = stats[t] * inv_n;
        float var = stats[64 + t] * inv_n - mu * mu;
        float sc = g[t] * rsqrtf(var + EPS);
        scb[t] = sc;
        shb[t] = be[t] - mu * sc;
    }
    __syncthreads();
    int nbase = blockIdx.x * 32;
    #pragma unroll 8
    for (int i = 0; i < 8; ++i) {
        int idx = t + i * 256;          // 0..2047
        int r = idx >> 6, c = idx & 63;
        int nn = nbase + r;
        float v = (nn < n_nodes) ? B[((size_t)nn << 6) + c] : 0.f;
        rows[r][c] = fmaxf(scb[c] * v + shb[c], 0.f);
    }
    __syncthreads();

    int w = t >> 6, j = t & 63;
    int rb = w * 8;
    // ---- m0: 8 nodes/wave, lane = output channel ----
    float acc0[8];
    float b0j = bm0[j];
    #pragma unroll
    for (int i = 0; i < 8; ++i) acc0[i] = b0j;
    #pragma unroll 4
    for (int k = 0; k < 64; k += 2) {
        float wv0 = Wm0[k * 64 + j];
        float wv1 = Wm0[(k + 1) * 64 + j];
        #pragma unroll
        for (int i = 0; i < 8; ++i) {
            float2 hv = *(const float2*)&rows[rb + i][k];
            acc0[i] = fmaf(hv.x, wv0, acc0[i]);
            acc0[i] = fmaf(hv.y, wv1, acc0[i]);
        }
    }
    #pragma unroll
    for (int i = 0; i < 8; ++i) rows[rb + i][j] = fmaxf(acc0[i], 0.f);
    __syncthreads();
    // ---- m1: half-wave h -> nodes rb+h*4.., ch2 = output channel ----
    int h = j >> 5, ch2 = j & 31;
    int rb1 = rb + h * 4;
    float acc2[4];
    float b1j = bm1[ch2];
    #pragma unroll
    for (int i = 0; i < 4; ++i) acc2[i] = b1j;
    #pragma unroll 4
    for (int k = 0; k < 64; k += 2) {
        float wv0 = Wm1[k * 32 + ch2];
        float wv1 = Wm1[(k + 1) * 32 + ch2];
        #pragma unroll
        for (int i = 0; i < 4; ++i) {
            float2 hv = *(const float2*)&rows[rb1 + i][k];
            acc2[i] = fmaf(hv.x, wv0, acc2[i]);
            acc2[i] = fmaf(hv.y, wv1, acc2[i]);
        }
    }
    // ---- m2: per-node dot over 32 channels via shuffle reduce ----
    float wm2 = Wm2[ch2];
    float z[4];
    #pragma unroll
    for (int i = 0; i < 4; ++i) z[i] = fmaxf(acc2[i], 0.f) * wm2;
    #pragma unroll
    for (int d = 1; d < 32; d <<= 1) {
        #pragma unroll
        for (int i = 0; i < 4; ++i) z[i] += __shfl_xor(z[i], d, 64);
    }
    if (ch2 == 0) {
        float bb = bm2[0];
        #pragma unroll
        for (int i = 0; i < 4; ++i) {
            int nn = nbase + rb1 + i;
            if (nn < n_nodes)
                out[nn] = 1.0f / (1.0f + __expf(-(z[i] + bb)));
        }
    }
}

extern "C" void kernel_launch(void* const* d_in, const int* in_sizes, int n_in,
                              void* d_out, int out_size, void* d_ws, size_t ws_size,
                              hipStream_t stream) {
    const float* x   = (const float*)d_in[0];
    const int*   src = (const int*)d_in[1];
    const int*   dst = (const int*)d_in[2];
    const float* W0  = (const float*)d_in[3];
    const float* b0  = (const float*)d_in[4];
    const float* W1  = (const float*)d_in[5];
    const float* b1  = (const float*)d_in[6];
    const float* g0  = (const float*)d_in[7];
    const float* be0 = (const float*)d_in[8];
    const float* g1  = (const float*)d_in[9];
    const float* be1 = (const float*)d_in[10];
    const float* Wm0 = (const float*)d_in[11];
    const float* bm0 = (const float*)d_in[12];
    const float* Wm1 = (const float*)d_in[13];
    const float* bm1 = (const float*)d_in[14];
    const float* Wm2 = (const float*)d_in[15];
    const float* bm2 = (const float*)d_in[16];

    int n = in_sizes[0] / 4;
    int e = in_sizes[1];
    float* out = (float*)d_out;

    int nb = (n + BSZ - 1) >> BSH;            // 391 buckets for n=100k

    char* ws = (char*)d_ws;
    auto alignup = [](size_t v) { return (v + 255) & ~(size_t)255; };
    size_t o = 0;
    int*      boff    = (int*)(ws + o);      o += alignup(513 * 4);
    int*      gcur    = (int*)(ws + o);      o += alignup(512 * 4);
    float*    stats   = (float*)(ws + o);    o += alignup(256 * 4);
    int*      row_ptr = (int*)(ws + o);      o += alignup((size_t)(n + 1) * 4);
    float*    dinv    = (float*)(ws + o);    o += alignup((size_t)n * 4);
    unsigned* bedges  = (unsigned*)(ws + o); o += alignup((size_t)nb * BCAP * 4);
    unsigned* csr     = (unsigned*)(ws + o); o += alignup((size_t)e * 4);
    __half*   A       = (__half*)(ws + o);   o += alignup((size_t)n * 64 * 2);
    float*    B       = (float*)(ws + o);

    int gN4    = (n + 3) / 4;
    int ntiles = (e + T1 - 1) / T1;           // 782 blocks
    int gMLP   = (n + 31) / 32;
    int gAGG   = (n + 63) / 64;               // one block per 64-node group

    (void)hipMemsetAsync(stats, 0, 256 * 4, stream);

    // ---- CSR build (bucketed, fixed-capacity reservation; once, reused) ----
    k_ginit<<<1, 512, 0, stream>>>(gcur);
    k_bucket<<<ntiles, 256, 0, stream>>>(src, dst, gcur, bedges, e, nb);
    k_bscan<<<1, 512, 0, stream>>>(gcur, boff, row_ptr, nb, n, e);
    k_build<<<nb, 256, 0, stream>>>(bedges, boff, row_ptr, csr, dinv, n);

    // ---- layer 1 ----
    k_lin0<<<gN4, 256, 0, stream>>>(x, W0, dinv, A, n);
    k_aggr<<<gAGG, 256, 0, stream>>>(row_ptr, csr, A, dinv, b0, B, stats, n);

    // ---- layer 2 (BN0+ReLU fused into lin1) ----
    k_lin1<<<2048, 256, 0, stream>>>(B, W1, dinv, stats, g0, be0, A, n);
    k_aggr<<<gAGG, 256, 0, stream>>>(row_ptr, csr, A, dinv, b1, B, stats + 128, n);

    // ---- MLP head (BN1+ReLU fused) ----
    k_mlp<<<gMLP, 256, 0, stream>>>(B, stats + 128, g1, be1,
                                    Wm0, bm0, Wm1, bm1, Wm2, bm2, out, n);
}

// Round 15
// 326.877 us; speedup vs baseline: 1.7973x; 1.0247x over previous
//
#include <hip/hip_runtime.h>
#include <hip/hip_fp16.h>
#include <math.h>

#define HD 64
#define EPS 1e-5f
#define BSH 8                   // bucket shift: 256 nodes per bucket
#define BSZ 256
#define T1 4096                 // edges per tile in k_bucket (16 per thread, in regs)
#define BCAP 10240              // fixed bucket capacity (mean 8192, sigma ~90 -> 22-sigma slack)
// packing: n <= 131072 (2^17) required: packed = (local_dst<<17) | src

__device__ __forceinline__ float atomAddF(float* p, float v) {
    return unsafeAtomicAdd(p, v);   // native global_atomic_add_f32 on gfx950
}

// ---------- CSR build (bucketed counting sort, fixed-capacity reservation) ----------

// init per-bucket global cursors to sparse bucket bases
__global__ __launch_bounds__(512) void k_ginit(int* __restrict__ gcur) {
    int t = threadIdx.x;
    gcur[t] = t * BCAP;
}

// pass 1: one-read bucketing. Each thread keeps its 16 edges in registers
// (int4 loads), LDS-hists, block reserves per-bucket space, scatters from regs.
__global__ __launch_bounds__(256) void k_bucket(const int* __restrict__ src,
        const int* __restrict__ dst, int* __restrict__ gcur,
        unsigned* __restrict__ bedges, int e, int nbuck) {
    __shared__ int hist[512];
    __shared__ int base[512];
    int t = threadIdx.x;
    int tile = blockIdx.x * T1;
    int lim = min(e - tile, T1);
    hist[t] = 0; hist[t + 256] = 0;
    __syncthreads();
    int d_[16], s_[16];
    bool full = (lim == T1);
    if (full) {
        const int4* d4 = (const int4*)(dst + tile);
        const int4* s4 = (const int4*)(src + tile);
        #pragma unroll
        for (int j = 0; j < 4; ++j) {
            int4 dv = d4[j * 256 + t];
            int4 sv = s4[j * 256 + t];
            d_[4 * j + 0] = dv.x; d_[4 * j + 1] = dv.y;
            d_[4 * j + 2] = dv.z; d_[4 * j + 3] = dv.w;
            s_[4 * j + 0] = sv.x; s_[4 * j + 1] = sv.y;
            s_[4 * j + 2] = sv.z; s_[4 * j + 3] = sv.w;
        }
        #pragma unroll
        for (int j = 0; j < 16; ++j) atomicAdd(&hist[d_[j] >> BSH], 1);
    } else {
        for (int j = t; j < lim; j += 256)
            atomicAdd(&hist[dst[tile + j] >> BSH], 1);
    }
    __syncthreads();
    for (int b = t; b < nbuck; b += 256) {
        int h = hist[b];
        base[b] = (h > 0) ? atomicAdd(&gcur[b], h) : 0;
        hist[b] = 0;                 // reuse as local cursor
    }
    __syncthreads();
    if (full) {
        #pragma unroll
        for (int j = 0; j < 16; ++j) {
            int bk = d_[j] >> BSH;
            int loc = atomicAdd(&hist[bk], 1);
            bedges[base[bk] + loc] =
                ((unsigned)(d_[j] & (BSZ - 1)) << 17) | (unsigned)s_[j];
        }
    } else {
        for (int j = t; j < lim; j += 256) {
            int d = dst[tile + j], s = src[tile + j];
            int bk = d >> BSH;
            int loc = atomicAdd(&hist[bk], 1);
            bedges[base[bk] + loc] = ((unsigned)(d & (BSZ - 1)) << 17) | (unsigned)s;
        }
    }
}

// scan bucket counts (derived from final gcur) -> compact offsets boff
__global__ __launch_bounds__(512) void k_bscan(const int* __restrict__ gcur,
        int* __restrict__ boff, int* __restrict__ row_ptr, int nb, int n, int e) {
    __shared__ int sc[512];
    int t = threadIdx.x;
    int v = (t < nb) ? (gcur[t] - t * BCAP) : 0;
    sc[t] = v;
    __syncthreads();
    int acc = v;
    for (int off = 1; off < 512; off <<= 1) {
        int x = (t >= off) ? sc[t - off] : 0;
        __syncthreads();
        acc += x;
        sc[t] = acc;
        __syncthreads();
    }
    boff[t] = acc - v;               // boff[nb] = e
    if (t == 0) row_ptr[n] = e;
}

// pass 2: one block per 256-node bucket -> row_ptr, dinv, csr (compact).
// uint4-vectorized passes over the sparse bucket region.
__global__ __launch_bounds__(256) void k_build(const unsigned* __restrict__ bedges,
        const int* __restrict__ boff, int* __restrict__ row_ptr,
        unsigned* __restrict__ csr, float* __restrict__ dinv, int n) {
    __shared__ int hist[BSZ];
    __shared__ int cur[BSZ];
    __shared__ int sc[256];
    int b = blockIdx.x, t = threadIdx.x;
    int nodebase = b << BSH;
    int cbase = boff[b];
    int cnt = boff[b + 1] - cbase;
    const unsigned* bed = bedges + (size_t)b * BCAP;
    hist[t] = 0;
    __syncthreads();
    int cnt4 = cnt & ~3;
    for (int jj = t * 4; jj < cnt4; jj += 1024) {
        uint4 p = *(const uint4*)(bed + jj);
        atomicAdd(&hist[p.x >> 17], 1); atomicAdd(&hist[p.y >> 17], 1);
        atomicAdd(&hist[p.z >> 17], 1); atomicAdd(&hist[p.w >> 17], 1);
    }
    for (int jj = cnt4 + t; jj < cnt; jj += 256)
        atomicAdd(&hist[bed[jj] >> 17], 1);
    __syncthreads();
    int a = hist[t];
    sc[t] = a;
    __syncthreads();
    int acc = a;
    for (int off = 1; off < 256; off <<= 1) {
        int x = (t >= off) ? sc[t - off] : 0;
        __syncthreads();
        acc += x;
        sc[t] = acc;
        __syncthreads();
    }
    int e0 = cbase + acc - a;        // exclusive
    cur[t] = e0;
    int node = nodebase + t;
    if (node < n) { row_ptr[node] = e0; dinv[node] = rsqrtf((float)(a + 1)); }
    __syncthreads();
    for (int jj = t * 4; jj < cnt4; jj += 1024) {
        uint4 p = *(const uint4*)(bed + jj);
        int p0 = atomicAdd(&cur[p.x >> 17], 1); csr[p0] = p.x;
        int p1 = atomicAdd(&cur[p.y >> 17], 1); csr[p1] = p.y;
        int p2 = atomicAdd(&cur[p.z >> 17], 1); csr[p2] = p.z;
        int p3 = atomicAdd(&cur[p.w >> 17], 1); csr[p3] = p.w;
    }
    for (int jj = cnt4 + t; jj < cnt; jj += 256) {
        unsigned p = bed[jj];
        int pos = atomicAdd(&cur[p >> 17], 1);
        csr[pos] = p;
    }
}

// ---------- layer compute ----------
// A: fp16, linear rows A[n*64+c] (128B per row)

// A[n][c] = half( dinv[n] * sum_k x[n][k]*W0[k][c] )
__global__ __launch_bounds__(256) void k_lin0(const float* __restrict__ x,
        const float* __restrict__ W0, const float* __restrict__ dinv,
        __half* __restrict__ A, int n_nodes) {
    __shared__ float w[4 * HD];
    int t = threadIdx.x;
    w[t] = W0[t];
    __syncthreads();
    int n = blockIdx.x * 4 + (t >> 6);
    int c = t & 63;
    if (n >= n_nodes) return;
    float x0 = x[n * 4 + 0], x1 = x[n * 4 + 1], x2 = x[n * 4 + 2], x3 = x[n * 4 + 3];
    float v = x0 * w[c] + x1 * w[64 + c] + x2 * w[128 + c] + x3 * w[192 + c];
    A[((size_t)n << 6) + c] = __float2half(v * dinv[n]);
}

// edge-parallel aggregation: one block per 64-node group, fp32 LDS accumulator.
// 16-lane groups: each lane loads 8B (4 halves) of the 128B row -> one wave
// instruction covers 4 edges; 16-deep unroll -> 16 gathers in flight per group.
// Register-accumulate runs of equal dst (sorted), flush 4 LDS atomics on change.
__global__ __launch_bounds__(256) void k_aggr(const int* __restrict__ row_ptr,
        const unsigned* __restrict__ pedges, const __half* __restrict__ A,
        const float* __restrict__ dinv, const float* __restrict__ bias,
        float* __restrict__ B, float* __restrict__ stats, int n_nodes) {
    __shared__ float acc[64 * 65];
    __shared__ float ls[4][64], ls2[4][64];
    int t = threadIdx.x;
    for (int i = t; i < 64 * 65; i += 256) acc[i] = 0.f;
    int nodebase = blockIdx.x << 6;
    int nend = min(nodebase + 64, n_nodes);
    int ebeg = row_ptr[nodebase];
    int eend = row_ptr[nend];
    int nedges = eend - ebeg;
    __syncthreads();

    int wv = t >> 6, lane = t & 63;
    int sub = lane >> 4, ch = lane & 15;       // 16-lane group; ch*4 = channel base
    int s = wv * 4 + sub;                      // stream 0..15
    int sbeg = ebeg + (int)(((long long)nedges * s) >> 4);
    int send = ebeg + (int)(((long long)nedges * (s + 1)) >> 4);
    const uint2* A2 = (const uint2*)A;         // 16 uint2 per 64-half row

    float a0 = 0.f, a1 = 0.f, a2 = 0.f, a3 = 0.f;
    int cur = -1;

    #define FLUSH() if (cur >= 0) {                                            \
        int o_ = cur * 65 + (ch << 2);                                         \
        atomicAdd(&acc[o_ + 0], a0); atomicAdd(&acc[o_ + 1], a1);              \
        atomicAdd(&acc[o_ + 2], a2); atomicAdd(&acc[o_ + 3], a3); }

    #define PROC(P, U) {                                                       \
        int d_ = (int)((P) >> 17) & 63;                                        \
        if (d_ != cur) { FLUSH(); a0 = a1 = a2 = a3 = 0.f; cur = d_; }         \
        float2 f01_ = __half22float2(*(const __half2*)&(U).x);                 \
        float2 f23_ = __half22float2(*(const __half2*)&(U).y);                 \
        a0 += f01_.x; a1 += f01_.y; a2 += f23_.x; a3 += f23_.y; }

    int j = sbeg;
    for (; j + 16 <= send; j += 16) {
        unsigned p[16];
        uint2 u[16];
        #pragma unroll
        for (int k = 0; k < 16; ++k) p[k] = pedges[j + k];
        #pragma unroll
        for (int k = 0; k < 16; ++k)
            u[k] = A2[(((size_t)(p[k] & 0x1FFFFu)) << 4) + ch];
        #pragma unroll
        for (int k = 0; k < 16; ++k) PROC(p[k], u[k]);
    }
    for (; j < send; ++j) {
        unsigned p0 = pedges[j];
        uint2 u0 = A2[(((size_t)(p0 & 0x1FFFFu)) << 4) + ch];
        PROC(p0, u0);
    }
    FLUSH();
    #undef PROC
    #undef FLUSH
    __syncthreads();

    // finalize: wave wv handles rows wv, wv+4, ... ; lane = channel
    int c = lane;
    float st = 0.f, st2 = 0.f;
    for (int r = wv; r < 64; r += 4) {
        int node = nodebase + r;
        if (node < n_nodes) {
            float v = acc[r * 65 + c] + __half2float(A[((size_t)node << 6) + c]);
            v = dinv[node] * v + bias[c];
            B[((size_t)node << 6) + c] = v;
            st += v; st2 += v * v;
        }
    }
    ls[wv][c] = st; ls2[wv][c] = st2;
    __syncthreads();
    if (t < 64) {
        atomAddF(&stats[t], ls[0][t] + ls[1][t] + ls[2][t] + ls[3][t]);
        atomAddF(&stats[64 + t], ls2[0][t] + ls2[1][t] + ls2[2][t] + ls2[3][t]);
    }
}

// A(half) <- dinv[n] * (relu(bn(B)) @ W1)   (BN0+ReLU fused into row staging)
// LDS-BW optimized: lane = (node_sub, channel-quad); per k-step one broadcast
// rows read + one ds_read_b128 of W1[k][quad*4..+3] + 4 FMA. 16 nodes/iter.
__global__ __launch_bounds__(256) void k_lin1(const float* __restrict__ B,
        const float* __restrict__ W, const float* __restrict__ dinv,
        const float* __restrict__ stats, const float* __restrict__ g,
        const float* __restrict__ be, __half* __restrict__ A, int n_nodes) {
    __shared__ float w[HD * HD];
    __shared__ float rows[16][65];
    __shared__ float scb[64], shb[64];
    int t = threadIdx.x;
    for (int i = t; i < HD * HD; i += 256) w[i] = W[i];
    if (t < 64) {
        float inv_n = 1.0f / (float)n_nodes;
        float mu = stats[t] * inv_n;
        float var = stats[64 + t] * inv_n - mu * mu;
        float sc = g[t] * rsqrtf(var + EPS);
        scb[t] = sc;
        shb[t] = be[t] - mu * sc;
    }
    int wv = t >> 6, lane = t & 63;
    int nsub = lane >> 4, quad = lane & 15;
    const float4* w4 = (const float4*)w;
    int ngroups = (n_nodes + 15) >> 4;
    for (int gidx = blockIdx.x; gidx < ngroups; gidx += gridDim.x) {
        __syncthreads();                 // rows reuse + first-iter w/scb barrier
        int nb0 = gidx << 4;
        #pragma unroll
        for (int i = 0; i < 4; ++i) {
            int idx = t + (i << 8);      // 0..1023
            int r = idx >> 6, c = idx & 63;
            int nn = nb0 + r;
            float v = (nn < n_nodes) ? B[((size_t)nn << 6) + c] : 0.f;
            rows[r][c] = fmaxf(scb[c] * v + shb[c], 0.f);
        }
        __syncthreads();
        int r = (wv << 2) + nsub;
        int node = nb0 + r;
        if (node < n_nodes) {
            float a0 = 0.f, a1 = 0.f, a2 = 0.f, a3 = 0.f;
            #pragma unroll 8
            for (int k = 0; k < 64; ++k) {
                float hv = rows[r][k];
                float4 wq = w4[(k << 4) + quad];
                a0 = fmaf(hv, wq.x, a0); a1 = fmaf(hv, wq.y, a1);
                a2 = fmaf(hv, wq.z, a2); a3 = fmaf(hv, wq.w, a3);
            }
            float dv = dinv[node];
            __half2 h01 = __floats2half2_rn(a0 * dv, a1 * dv);
            __half2 h23 = __floats2half2_rn(a2 * dv, a3 * dv);
            uint2 uu;
            uu.x = *(unsigned*)&h01;
            uu.y = *(unsigned*)&h23;
            *(uint2*)(A + ((size_t)node << 6) + (quad << 2)) = uu;
        }
    }
}

// fused MLP head, weight-coalesced: block = 32 nodes, wave = 8 nodes,
// lane = OUTPUT channel -> Wm0[k*64+j] is a coalesced 256B vector load;
// h[k] comes from LDS broadcast. m1: half-wave = 4 nodes x 32 channels.
// m2: shuffle reduce over the 32-lane half.
__global__ __launch_bounds__(256) void k_mlp(const float* __restrict__ B,
        const float* __restrict__ stats, const float* __restrict__ g,
        const float* __restrict__ be,
        const float* __restrict__ Wm0, const float* __restrict__ bm0,
        const float* __restrict__ Wm1, const float* __restrict__ bm1,
        const float* __restrict__ Wm2, const float* __restrict__ bm2,
        float* __restrict__ out, int n_nodes) {
    __shared__ float rows[32][66];      // 66: even stride, 8B-aligned float2
    __shared__ float scb[64], shb[64];
    int t = threadIdx.x;
    if (t < 64) {
        float inv_n = 1.0f / (float)n_nodes;
        float mu = stats[t] * inv_n;
        float var = stats[64 + t] * inv_n - mu * mu;
        float sc = g[t] * rsqrtf(var + EPS);
        scb[t] = sc;
        shb[t] = be[t] - mu * sc;
    }
    __syncthreads();
    int nbase = blockIdx.x * 32;
    #pragma unroll 8
    for (int i = 0; i < 8; ++i) {
        int idx = t + i * 256;          // 0..2047
        int r = idx >> 6, c = idx & 63;
        int nn = nbase + r;
        float v = (nn < n_nodes) ? B[((size_t)nn << 6) + c] : 0.f;
        rows[r][c] = fmaxf(scb[c] * v + shb[c], 0.f);
    }
    __syncthreads();

    int w = t >> 6, j = t & 63;
    int rb = w * 8;
    // ---- m0: 8 nodes/wave, lane = output channel ----
    float acc0[8];
    float b0j = bm0[j];
    #pragma unroll
    for (int i = 0; i < 8; ++i) acc0[i] = b0j;
    #pragma unroll 4
    for (int k = 0; k < 64; k += 2) {
        float wv0 = Wm0[k * 64 + j];
        float wv1 = Wm0[(k + 1) * 64 + j];
        #pragma unroll
        for (int i = 0; i < 8; ++i) {
            float2 hv = *(const float2*)&rows[rb + i][k];
            acc0[i] = fmaf(hv.x, wv0, acc0[i]);
            acc0[i] = fmaf(hv.y, wv1, acc0[i]);
        }
    }
    #pragma unroll
    for (int i = 0; i < 8; ++i) rows[rb + i][j] = fmaxf(acc0[i], 0.f);
    __syncthreads();
    // ---- m1: half-wave h -> nodes rb+h*4.., ch2 = output channel ----
    int h = j >> 5, ch2 = j & 31;
    int rb1 = rb + h * 4;
    float acc2[4];
    float b1j = bm1[ch2];
    #pragma unroll
    for (int i = 0; i < 4; ++i) acc2[i] = b1j;
    #pragma unroll 4
    for (int k = 0; k < 64; k += 2) {
        float wv0 = Wm1[k * 32 + ch2];
        float wv1 = Wm1[(k + 1) * 32 + ch2];
        #pragma unroll
        for (int i = 0; i < 4; ++i) {
            float2 hv = *(const float2*)&rows[rb1 + i][k];
            acc2[i] = fmaf(hv.x, wv0, acc2[i]);
            acc2[i] = fmaf(hv.y, wv1, acc2[i]);
        }
    }
    // ---- m2: per-node dot over 32 channels via shuffle reduce ----
    float wm2 = Wm2[ch2];
    float z[4];
    #pragma unroll
    for (int i = 0; i < 4; ++i) z[i] = fmaxf(acc2[i], 0.f) * wm2;
    #pragma unroll
    for (int d = 1; d < 32; d <<= 1) {
        #pragma unroll
        for (int i = 0; i < 4; ++i) z[i] += __shfl_xor(z[i], d, 64);
    }
    if (ch2 == 0) {
        float bb = bm2[0];
        #pragma unroll
        for (int i = 0; i < 4; ++i) {
            int nn = nbase + rb1 + i;
            if (nn < n_nodes)
                out[nn] = 1.0f / (1.0f + __expf(-(z[i] + bb)));
        }
    }
}

extern "C" void kernel_launch(void* const* d_in, const int* in_sizes, int n_in,
                              void* d_out, int out_size, void* d_ws, size_t ws_size,
                              hipStream_t stream) {
    const float* x   = (const float*)d_in[0];
    const int*   src = (const int*)d_in[1];
    const int*   dst = (const int*)d_in[2];
    const float* W0  = (const float*)d_in[3];
    const float* b0  = (const float*)d_in[4];
    const float* W1  = (const float*)d_in[5];
    const float* b1  = (const float*)d_in[6];
    const float* g0  = (const float*)d_in[7];
    const float* be0 = (const float*)d_in[8];
    const float* g1  = (const float*)d_in[9];
    const float* be1 = (const float*)d_in[10];
    const float* Wm0 = (const float*)d_in[11];
    const float* bm0 = (const float*)d_in[12];
    const float* Wm1 = (const float*)d_in[13];
    const float* bm1 = (const float*)d_in[14];
    const float* Wm2 = (const float*)d_in[15];
    const float* bm2 = (const float*)d_in[16];

    int n = in_sizes[0] / 4;
    int e = in_sizes[1];
    float* out = (float*)d_out;

    int nb = (n + BSZ - 1) >> BSH;            // 391 buckets for n=100k

    char* ws = (char*)d_ws;
    auto alignup = [](size_t v) { return (v + 255) & ~(size_t)255; };
    size_t o = 0;
    int*      boff    = (int*)(ws + o);      o += alignup(513 * 4);
    int*      gcur    = (int*)(ws + o);      o += alignup(512 * 4);
    float*    stats   = (float*)(ws + o);    o += alignup(256 * 4);
    int*      row_ptr = (int*)(ws + o);      o += alignup((size_t)(n + 1) * 4);
    float*    dinv    = (float*)(ws + o);    o += alignup((size_t)n * 4);
    unsigned* bedges  = (unsigned*)(ws + o); o += alignup((size_t)nb * BCAP * 4);
    unsigned* csr     = (unsigned*)(ws + o); o += alignup((size_t)e * 4);
    __half*   A       = (__half*)(ws + o);   o += alignup((size_t)n * 64 * 2);
    float*    B       = (float*)(ws + o);

    int gN4    = (n + 3) / 4;
    int ntiles = (e + T1 - 1) / T1;           // 782 blocks
    int gMLP   = (n + 31) / 32;
    int gAGG   = (n + 63) / 64;               // one block per 64-node group

    (void)hipMemsetAsync(stats, 0, 256 * 4, stream);

    // ---- CSR build (bucketed, fixed-capacity reservation; once, reused) ----
    k_ginit<<<1, 512, 0, stream>>>(gcur);
    k_bucket<<<ntiles, 256, 0, stream>>>(src, dst, gcur, bedges, e, nb);
    k_bscan<<<1, 512, 0, stream>>>(gcur, boff, row_ptr, nb, n, e);
    k_build<<<nb, 256, 0, stream>>>(bedges, boff, row_ptr, csr, dinv, n);

    // ---- layer 1 ----
    k_lin0<<<gN4, 256, 0, stream>>>(x, W0, dinv, A, n);
    k_aggr<<<gAGG, 256, 0, stream>>>(row_ptr, csr, A, dinv, b0, B, stats, n);

    // ---- layer 2 (BN0+ReLU fused into lin1) ----
    k_lin1<<<2048, 256, 0, stream>>>(B, W1, dinv, stats, g0, be0, A, n);
    k_aggr<<<gAGG, 256, 0, stream>>>(row_ptr, csr, A, dinv, b1, B, stats + 128, n);

    // ---- MLP head (BN1+ReLU fused) ----
    k_mlp<<<gMLP, 256, 0, stream>>>(B, stats + 128, g1, be1,
                                    Wm0, bm0, Wm1, bm1, Wm2, bm2, out, n);
}

// Round 16
// 325.802 us; speedup vs baseline: 1.8032x; 1.0033x over previous
//
#include <hip/hip_runtime.h>
#include <hip/hip_fp16.h>
#include <math.h>

#define HD 64
#define EPS 1e-5f
#define BSH 8                   // bucket shift: 256 nodes per bucket
#define BSZ 256
#define T1 4096                 // edges per tile in k_bucket (16 per thread, in regs)
#define BCAP 10240              // fixed bucket capacity (mean 8192, sigma ~90 -> 22-sigma slack)
// packing: n <= 131072 (2^17) required: packed = (local_dst<<17) | src

__device__ __forceinline__ float atomAddF(float* p, float v) {
    return unsafeAtomicAdd(p, v);   // native global_atomic_add_f32 on gfx950
}

// ---------- CSR build (bucketed counting sort, fixed-capacity reservation) ----------

// pass 1: one-read bucketing. gcur starts ZERO (memset); reservation base is
// b*BCAP + atomicAdd(&gcur[b], h), so gcur ends holding pure bucket counts.
__global__ __launch_bounds__(256) void k_bucket(const int* __restrict__ src,
        const int* __restrict__ dst, int* __restrict__ gcur,
        unsigned* __restrict__ bedges, int e, int nbuck) {
    __shared__ int hist[512];
    __shared__ int base[512];
    int t = threadIdx.x;
    int tile = blockIdx.x * T1;
    int lim = min(e - tile, T1);
    hist[t] = 0; hist[t + 256] = 0;
    __syncthreads();
    int d_[16], s_[16];
    bool full = (lim == T1);
    if (full) {
        const int4* d4 = (const int4*)(dst + tile);
        const int4* s4 = (const int4*)(src + tile);
        #pragma unroll
        for (int j = 0; j < 4; ++j) {
            int4 dv = d4[j * 256 + t];
            int4 sv = s4[j * 256 + t];
            d_[4 * j + 0] = dv.x; d_[4 * j + 1] = dv.y;
            d_[4 * j + 2] = dv.z; d_[4 * j + 3] = dv.w;
            s_[4 * j + 0] = sv.x; s_[4 * j + 1] = sv.y;
            s_[4 * j + 2] = sv.z; s_[4 * j + 3] = sv.w;
        }
        #pragma unroll
        for (int j = 0; j < 16; ++j) atomicAdd(&hist[d_[j] >> BSH], 1);
    } else {
        for (int j = t; j < lim; j += 256)
            atomicAdd(&hist[dst[tile + j] >> BSH], 1);
    }
    __syncthreads();
    for (int b = t; b < nbuck; b += 256) {
        int h = hist[b];
        base[b] = (h > 0) ? (b * BCAP + atomicAdd(&gcur[b], h)) : 0;
        hist[b] = 0;                 // reuse as local cursor
    }
    __syncthreads();
    if (full) {
        #pragma unroll
        for (int j = 0; j < 16; ++j) {
            int bk = d_[j] >> BSH;
            int loc = atomicAdd(&hist[bk], 1);
            bedges[base[bk] + loc] =
                ((unsigned)(d_[j] & (BSZ - 1)) << 17) | (unsigned)s_[j];
        }
    } else {
        for (int j = t; j < lim; j += 256) {
            int d = dst[tile + j], s = src[tile + j];
            int bk = d >> BSH;
            int loc = atomicAdd(&hist[bk], 1);
            bedges[base[bk] + loc] = ((unsigned)(d & (BSZ - 1)) << 17) | (unsigned)s;
        }
    }
}

// pass 2 (fused): per-block bucket-count scan -> cbase; node hist+scan ->
// row_ptr, dinv, compact csr; epilogue = lin0 for this block's 256 nodes:
// A[node][c] = half(dinv * sum_k x[node][k]*W0[k][c])
__global__ __launch_bounds__(256) void k_build(const unsigned* __restrict__ bedges,
        const int* __restrict__ gcur, int* __restrict__ row_ptr,
        unsigned* __restrict__ csr, float* __restrict__ dinv,
        const float* __restrict__ x, const float* __restrict__ W0,
        __half* __restrict__ A, int n, int nb, int e) {
    __shared__ int hist[BSZ];
    __shared__ int cur[BSZ];
    __shared__ int sc[256];
    __shared__ int boffL[512];
    __shared__ float w0s[256];
    __shared__ float dinvs[BSZ];
    int b = blockIdx.x, t = threadIdx.x;
    int nodebase = b << BSH;

    // ---- bucket-count prefix scan (512 entries via 256 threads x 2) ----
    int c0 = (2 * t < nb) ? gcur[2 * t] : 0;
    int c1 = (2 * t + 1 < nb) ? gcur[2 * t + 1] : 0;
    int ps = c0 + c1;
    sc[t] = ps;
    w0s[t] = W0[t];
    __syncthreads();
    int acc = ps;
    for (int off = 1; off < 256; off <<= 1) {
        int xv = (t >= off) ? sc[t - off] : 0;
        __syncthreads();
        acc += xv;
        sc[t] = acc;
        __syncthreads();
    }
    boffL[2 * t] = acc - ps;
    boffL[2 * t + 1] = acc - ps + c0;
    if (t == 0 && b == 0) row_ptr[n] = e;
    __syncthreads();
    int cbase = boffL[b];
    int cnt = (b < nb) ? gcur[b] : 0;
    const unsigned* bed = bedges + (size_t)b * BCAP;

    // ---- node histogram ----
    hist[t] = 0;
    __syncthreads();
    int cnt4 = cnt & ~3;
    for (int jj = t * 4; jj < cnt4; jj += 1024) {
        uint4 p = *(const uint4*)(bed + jj);
        atomicAdd(&hist[p.x >> 17], 1); atomicAdd(&hist[p.y >> 17], 1);
        atomicAdd(&hist[p.z >> 17], 1); atomicAdd(&hist[p.w >> 17], 1);
    }
    for (int jj = cnt4 + t; jj < cnt; jj += 256)
        atomicAdd(&hist[bed[jj] >> 17], 1);
    __syncthreads();
    int a = hist[t];
    sc[t] = a;
    __syncthreads();
    int acc2 = a;
    for (int off = 1; off < 256; off <<= 1) {
        int xv = (t >= off) ? sc[t - off] : 0;
        __syncthreads();
        acc2 += xv;
        sc[t] = acc2;
        __syncthreads();
    }
    int e0 = cbase + acc2 - a;       // exclusive
    cur[t] = e0;
    float dv = rsqrtf((float)(a + 1));
    dinvs[t] = dv;
    int node = nodebase + t;
    if (node < n) { row_ptr[node] = e0; dinv[node] = dv; }
    __syncthreads();

    // ---- csr scatter (dst-sorted compact) ----
    for (int jj = t * 4; jj < cnt4; jj += 1024) {
        uint4 p = *(const uint4*)(bed + jj);
        int p0 = atomicAdd(&cur[p.x >> 17], 1); csr[p0] = p.x;
        int p1 = atomicAdd(&cur[p.y >> 17], 1); csr[p1] = p.y;
        int p2 = atomicAdd(&cur[p.z >> 17], 1); csr[p2] = p.z;
        int p3 = atomicAdd(&cur[p.w >> 17], 1); csr[p3] = p.w;
    }
    for (int jj = cnt4 + t; jj < cnt; jj += 256) {
        unsigned p = bed[jj];
        int pos = atomicAdd(&cur[p >> 17], 1);
        csr[pos] = p;
    }
    __syncthreads();

    // ---- fused lin0 for this block's nodes ----
    int wv = t >> 6, c = t & 63;
    for (int r = wv; r < BSZ; r += 4) {
        int nd = nodebase + r;
        if (nd >= n) continue;
        float4 xv = *(const float4*)(x + nd * 4);    // wave-uniform -> scalar loads
        float v = xv.x * w0s[c] + xv.y * w0s[64 + c]
                + xv.z * w0s[128 + c] + xv.w * w0s[192 + c];
        A[((size_t)nd << 6) + c] = __float2half(v * dinvs[r]);
    }
}

// ---------- layer compute ----------
// A: fp16, linear rows A[n*64+c] (128B per row)

// edge-parallel aggregation: one block per 64-node group, fp32 LDS accumulator.
// 16-lane groups: each lane loads 8B (4 halves) of the 128B row -> one wave
// instruction covers 4 edges; 16-deep unroll -> 16 gathers in flight per group.
// Register-accumulate runs of equal dst (sorted), flush 4 LDS atomics on change.
__global__ __launch_bounds__(256) void k_aggr(const int* __restrict__ row_ptr,
        const unsigned* __restrict__ pedges, const __half* __restrict__ A,
        const float* __restrict__ dinv, const float* __restrict__ bias,
        float* __restrict__ B, float* __restrict__ stats, int n_nodes) {
    __shared__ float acc[64 * 65];
    __shared__ float ls[4][64], ls2[4][64];
    int t = threadIdx.x;
    for (int i = t; i < 64 * 65; i += 256) acc[i] = 0.f;
    int nodebase = blockIdx.x << 6;
    int nend = min(nodebase + 64, n_nodes);
    int ebeg = row_ptr[nodebase];
    int eend = row_ptr[nend];
    int nedges = eend - ebeg;
    __syncthreads();

    int wv = t >> 6, lane = t & 63;
    int sub = lane >> 4, ch = lane & 15;       // 16-lane group; ch*4 = channel base
    int s = wv * 4 + sub;                      // stream 0..15
    int sbeg = ebeg + (int)(((long long)nedges * s) >> 4);
    int send = ebeg + (int)(((long long)nedges * (s + 1)) >> 4);
    const uint2* A2 = (const uint2*)A;         // 16 uint2 per 64-half row

    float a0 = 0.f, a1 = 0.f, a2 = 0.f, a3 = 0.f;
    int cur = -1;

    #define FLUSH() if (cur >= 0) {                                            \
        int o_ = cur * 65 + (ch << 2);                                         \
        atomicAdd(&acc[o_ + 0], a0); atomicAdd(&acc[o_ + 1], a1);              \
        atomicAdd(&acc[o_ + 2], a2); atomicAdd(&acc[o_ + 3], a3); }

    #define PROC(P, U) {                                                       \
        int d_ = (int)((P) >> 17) & 63;                                        \
        if (d_ != cur) { FLUSH(); a0 = a1 = a2 = a3 = 0.f; cur = d_; }         \
        float2 f01_ = __half22float2(*(const __half2*)&(U).x);                 \
        float2 f23_ = __half22float2(*(const __half2*)&(U).y);                 \
        a0 += f01_.x; a1 += f01_.y; a2 += f23_.x; a3 += f23_.y; }

    int j = sbeg;
    for (; j + 16 <= send; j += 16) {
        unsigned p[16];
        uint2 u[16];
        #pragma unroll
        for (int k = 0; k < 16; ++k) p[k] = pedges[j + k];
        #pragma unroll
        for (int k = 0; k < 16; ++k)
            u[k] = A2[(((size_t)(p[k] & 0x1FFFFu)) << 4) + ch];
        #pragma unroll
        for (int k = 0; k < 16; ++k) PROC(p[k], u[k]);
    }
    for (; j < send; ++j) {
        unsigned p0 = pedges[j];
        uint2 u0 = A2[(((size_t)(p0 & 0x1FFFFu)) << 4) + ch];
        PROC(p0, u0);
    }
    FLUSH();
    #undef PROC
    #undef FLUSH
    __syncthreads();

    // finalize: wave wv handles rows wv, wv+4, ... ; lane = channel
    int c = lane;
    float st = 0.f, st2 = 0.f;
    for (int r = wv; r < 64; r += 4) {
        int node = nodebase + r;
        if (node < n_nodes) {
            float v = acc[r * 65 + c] + __half2float(A[((size_t)node << 6) + c]);
            v = dinv[node] * v + bias[c];
            B[((size_t)node << 6) + c] = v;
            st += v; st2 += v * v;
        }
    }
    ls[wv][c] = st; ls2[wv][c] = st2;
    __syncthreads();
    if (t < 64) {
        atomAddF(&stats[t], ls[0][t] + ls[1][t] + ls[2][t] + ls[3][t]);
        atomAddF(&stats[64 + t], ls2[0][t] + ls2[1][t] + ls2[2][t] + ls2[3][t]);
    }
}

// A(half) <- dinv[n] * (relu(bn(B)) @ W1)   (BN0+ReLU fused into row staging)
// LDS-BW optimized: lane = (node_sub, channel-quad); per k-step one broadcast
// rows read + one ds_read_b128 of W1[k][quad*4..+3] + 4 FMA. 16 nodes/iter.
__global__ __launch_bounds__(256) void k_lin1(const float* __restrict__ B,
        const float* __restrict__ W, const float* __restrict__ dinv,
        const float* __restrict__ stats, const float* __restrict__ g,
        const float* __restrict__ be, __half* __restrict__ A, int n_nodes) {
    __shared__ float w[HD * HD];
    __shared__ float rows[16][65];
    __shared__ float scb[64], shb[64];
    int t = threadIdx.x;
    for (int i = t; i < HD * HD; i += 256) w[i] = W[i];
    if (t < 64) {
        float inv_n = 1.0f / (float)n_nodes;
        float mu = stats[t] * inv_n;
        float var = stats[64 + t] * inv_n - mu * mu;
        float sc = g[t] * rsqrtf(var + EPS);
        scb[t] = sc;
        shb[t] = be[t] - mu * sc;
    }
    int wv = t >> 6, lane = t & 63;
    int nsub = lane >> 4, quad = lane & 15;
    const float4* w4 = (const float4*)w;
    int ngroups = (n_nodes + 15) >> 4;
    for (int gidx = blockIdx.x; gidx < ngroups; gidx += gridDim.x) {
        __syncthreads();                 // rows reuse + first-iter w/scb barrier
        int nb0 = gidx << 4;
        #pragma unroll
        for (int i = 0; i < 4; ++i) {
            int idx = t + (i << 8);      // 0..1023
            int r = idx >> 6, c = idx & 63;
            int nn = nb0 + r;
            float v = (nn < n_nodes) ? B[((size_t)nn << 6) + c] : 0.f;
            rows[r][c] = fmaxf(scb[c] * v + shb[c], 0.f);
        }
        __syncthreads();
        int r = (wv << 2) + nsub;
        int node = nb0 + r;
        if (node < n_nodes) {
            float a0 = 0.f, a1 = 0.f, a2 = 0.f, a3 = 0.f;
            #pragma unroll 8
            for (int k = 0; k < 64; ++k) {
                float hv = rows[r][k];
                float4 wq = w4[(k << 4) + quad];
                a0 = fmaf(hv, wq.x, a0); a1 = fmaf(hv, wq.y, a1);
                a2 = fmaf(hv, wq.z, a2); a3 = fmaf(hv, wq.w, a3);
            }
            float dv = dinv[node];
            __half2 h01 = __floats2half2_rn(a0 * dv, a1 * dv);
            __half2 h23 = __floats2half2_rn(a2 * dv, a3 * dv);
            uint2 uu;
            uu.x = *(unsigned*)&h01;
            uu.y = *(unsigned*)&h23;
            *(uint2*)(A + ((size_t)node << 6) + (quad << 2)) = uu;
        }
    }
}

// fused MLP head, weight-coalesced: block = 32 nodes, wave = 8 nodes,
// lane = OUTPUT channel -> Wm0[k*64+j] is a coalesced 256B vector load;
// h[k] comes from LDS broadcast. m1: half-wave = 4 nodes x 32 channels.
// m2: shuffle reduce over the 32-lane half.
__global__ __launch_bounds__(256) void k_mlp(const float* __restrict__ B,
        const float* __restrict__ stats, const float* __restrict__ g,
        const float* __restrict__ be,
        const float* __restrict__ Wm0, const float* __restrict__ bm0,
        const float* __restrict__ Wm1, const float* __restrict__ bm1,
        const float* __restrict__ Wm2, const float* __restrict__ bm2,
        float* __restrict__ out, int n_nodes) {
    __shared__ float rows[32][66];      // 66: even stride, 8B-aligned float2
    __shared__ float scb[64], shb[64];
    int t = threadIdx.x;
    if (t < 64) {
        float inv_n = 1.0f / (float)n_nodes;
        float mu = stats[t] * inv_n;
        float var = stats[64 + t] * inv_n - mu * mu;
        float sc = g[t] * rsqrtf(var + EPS);
        scb[t] = sc;
        shb[t] = be[t] - mu * sc;
    }
    __syncthreads();
    int nbase = blockIdx.x * 32;
    #pragma unroll 8
    for (int i = 0; i < 8; ++i) {
        int idx = t + i * 256;          // 0..2047
        int r = idx >> 6, c = idx & 63;
        int nn = nbase + r;
        float v = (nn < n_nodes) ? B[((size_t)nn << 6) + c] : 0.f;
        rows[r][c] = fmaxf(scb[c] * v + shb[c], 0.f);
    }
    __syncthreads();

    int w = t >> 6, j = t & 63;
    int rb = w * 8;
    // ---- m0: 8 nodes/wave, lane = output channel ----
    float acc0[8];
    float b0j = bm0[j];
    #pragma unroll
    for (int i = 0; i < 8; ++i) acc0[i] = b0j;
    #pragma unroll 4
    for (int k = 0; k < 64; k += 2) {
        float wv0 = Wm0[k * 64 + j];
        float wv1 = Wm0[(k + 1) * 64 + j];
        #pragma unroll
        for (int i = 0; i < 8; ++i) {
            float2 hv = *(const float2*)&rows[rb + i][k];
            acc0[i] = fmaf(hv.x, wv0, acc0[i]);
            acc0[i] = fmaf(hv.y, wv1, acc0[i]);
        }
    }
    #pragma unroll
    for (int i = 0; i < 8; ++i) rows[rb + i][j] = fmaxf(acc0[i], 0.f);
    __syncthreads();
    // ---- m1: half-wave h -> nodes rb+h*4.., ch2 = output channel ----
    int h = j >> 5, ch2 = j & 31;
    int rb1 = rb + h * 4;
    float acc2[4];
    float b1j = bm1[ch2];
    #pragma unroll
    for (int i = 0; i < 4; ++i) acc2[i] = b1j;
    #pragma unroll 4
    for (int k = 0; k < 64; k += 2) {
        float wv0 = Wm1[k * 32 + ch2];
        float wv1 = Wm1[(k + 1) * 32 + ch2];
        #pragma unroll
        for (int i = 0; i < 4; ++i) {
            float2 hv = *(const float2*)&rows[rb1 + i][k];
            acc2[i] = fmaf(hv.x, wv0, acc2[i]);
            acc2[i] = fmaf(hv.y, wv1, acc2[i]);
        }
    }
    // ---- m2: per-node dot over 32 channels via shuffle reduce ----
    float wm2 = Wm2[ch2];
    float z[4];
    #pragma unroll
    for (int i = 0; i < 4; ++i) z[i] = fmaxf(acc2[i], 0.f) * wm2;
    #pragma unroll
    for (int d = 1; d < 32; d <<= 1) {
        #pragma unroll
        for (int i = 0; i < 4; ++i) z[i] += __shfl_xor(z[i], d, 64);
    }
    if (ch2 == 0) {
        float bb = bm2[0];
        #pragma unroll
        for (int i = 0; i < 4; ++i) {
            int nn = nbase + rb1 + i;
            if (nn < n_nodes)
                out[nn] = 1.0f / (1.0f + __expf(-(z[i] + bb)));
        }
    }
}

extern "C" void kernel_launch(void* const* d_in, const int* in_sizes, int n_in,
                              void* d_out, int out_size, void* d_ws, size_t ws_size,
                              hipStream_t stream) {
    const float* x   = (const float*)d_in[0];
    const int*   src = (const int*)d_in[1];
    const int*   dst = (const int*)d_in[2];
    const float* W0  = (const float*)d_in[3];
    const float* b0  = (const float*)d_in[4];
    const float* W1  = (const float*)d_in[5];
    const float* b1  = (const float*)d_in[6];
    const float* g0  = (const float*)d_in[7];
    const float* be0 = (const float*)d_in[8];
    const float* g1  = (const float*)d_in[9];
    const float* be1 = (const float*)d_in[10];
    const float* Wm0 = (const float*)d_in[11];
    const float* bm0 = (const float*)d_in[12];
    const float* Wm1 = (const float*)d_in[13];
    const float* bm1 = (const float*)d_in[14];
    const float* Wm2 = (const float*)d_in[15];
    const float* bm2 = (const float*)d_in[16];

    int n = in_sizes[0] / 4;
    int e = in_sizes[1];
    float* out = (float*)d_out;

    int nb = (n + BSZ - 1) >> BSH;            // 391 buckets for n=100k

    char* ws = (char*)d_ws;
    auto alignup = [](size_t v) { return (v + 255) & ~(size_t)255; };
    size_t o = 0;
    int*      gcur    = (int*)(ws + o);      o += alignup(512 * 4);   // contiguous with stats
    float*    stats   = (float*)(ws + o);    o += alignup(256 * 4);
    int*      row_ptr = (int*)(ws + o);      o += alignup((size_t)(n + 1) * 4);
    float*    dinv    = (float*)(ws + o);    o += alignup((size_t)n * 4);
    unsigned* bedges  = (unsigned*)(ws + o); o += alignup((size_t)nb * BCAP * 4);
    unsigned* csr     = (unsigned*)(ws + o); o += alignup((size_t)e * 4);
    __half*   A       = (__half*)(ws + o);   o += alignup((size_t)n * 64 * 2);
    float*    B       = (float*)(ws + o);

    int ntiles = (e + T1 - 1) / T1;           // 782 blocks
    int gMLP   = (n + 31) / 32;
    int gAGG   = (n + 63) / 64;               // one block per 64-node group

    (void)hipMemsetAsync(gcur, 0, (512 + 256) * 4, stream);   // gcur + stats

    // ---- CSR build + lin0 (fused; once, reused by both layers) ----
    k_bucket<<<ntiles, 256, 0, stream>>>(src, dst, gcur, bedges, e, nb);
    k_build<<<nb, 256, 0, stream>>>(bedges, gcur, row_ptr, csr, dinv,
                                    x, W0, A, n, nb, e);

    // ---- layer 1 ----
    k_aggr<<<gAGG, 256, 0, stream>>>(row_ptr, csr, A, dinv, b0, B, stats, n);

    // ---- layer 2 (BN0+ReLU fused into lin1) ----
    k_lin1<<<2048, 256, 0, stream>>>(B, W1, dinv, stats, g0, be0, A, n);
    k_aggr<<<gAGG, 256, 0, stream>>>(row_ptr, csr, A, dinv, b1, B, stats + 128, n);

    // ---- MLP head (BN1+ReLU fused) ----
    k_mlp<<<gMLP, 256, 0, stream>>>(B, stats + 128, g1, be1,
                                    Wm0, bm0, Wm1, bm1, Wm2, bm2, out, n);
}

// Round 17
// 323.769 us; speedup vs baseline: 1.8146x; 1.0063x over previous
//
#include <hip/hip_runtime.h>
#include <hip/hip_fp16.h>
#include <math.h>

#define HD 64
#define EPS 1e-5f
#define BSH 8                   // bucket shift: 256 nodes per bucket
#define BSZ 256
#define T1 4096                 // edges per tile in k_bucket (16 per thread, in regs)
#define BCAP 10240              // fixed bucket capacity (mean 8192, sigma ~90 -> 22-sigma slack)
// packing: n <= 131072 (2^17) required: packed = (local_dst<<17) | src

__device__ __forceinline__ float atomAddF(float* p, float v) {
    return unsafeAtomicAdd(p, v);   // native global_atomic_add_f32 on gfx950
}

// ---------- CSR build (bucketed counting sort, fixed-capacity reservation) ----------

// pass 1: one-read bucketing. gcur starts ZERO (memset); reservation base is
// b*BCAP + atomicAdd(&gcur[b], h), so gcur ends holding pure bucket counts.
__global__ __launch_bounds__(256) void k_bucket(const int* __restrict__ src,
        const int* __restrict__ dst, int* __restrict__ gcur,
        unsigned* __restrict__ bedges, int e, int nbuck) {
    __shared__ int hist[512];
    __shared__ int base[512];
    int t = threadIdx.x;
    int tile = blockIdx.x * T1;
    int lim = min(e - tile, T1);
    hist[t] = 0; hist[t + 256] = 0;
    __syncthreads();
    int d_[16], s_[16];
    bool full = (lim == T1);
    if (full) {
        const int4* d4 = (const int4*)(dst + tile);
        const int4* s4 = (const int4*)(src + tile);
        #pragma unroll
        for (int j = 0; j < 4; ++j) {
            int4 dv = d4[j * 256 + t];
            int4 sv = s4[j * 256 + t];
            d_[4 * j + 0] = dv.x; d_[4 * j + 1] = dv.y;
            d_[4 * j + 2] = dv.z; d_[4 * j + 3] = dv.w;
            s_[4 * j + 0] = sv.x; s_[4 * j + 1] = sv.y;
            s_[4 * j + 2] = sv.z; s_[4 * j + 3] = sv.w;
        }
        #pragma unroll
        for (int j = 0; j < 16; ++j) atomicAdd(&hist[d_[j] >> BSH], 1);
    } else {
        for (int j = t; j < lim; j += 256)
            atomicAdd(&hist[dst[tile + j] >> BSH], 1);
    }
    __syncthreads();
    for (int b = t; b < nbuck; b += 256) {
        int h = hist[b];
        base[b] = (h > 0) ? (b * BCAP + atomicAdd(&gcur[b], h)) : 0;
        hist[b] = 0;                 // reuse as local cursor
    }
    __syncthreads();
    if (full) {
        #pragma unroll
        for (int j = 0; j < 16; ++j) {
            int bk = d_[j] >> BSH;
            int loc = atomicAdd(&hist[bk], 1);
            bedges[base[bk] + loc] =
                ((unsigned)(d_[j] & (BSZ - 1)) << 17) | (unsigned)s_[j];
        }
    } else {
        for (int j = t; j < lim; j += 256) {
            int d = dst[tile + j], s = src[tile + j];
            int bk = d >> BSH;
            int loc = atomicAdd(&hist[bk], 1);
            bedges[base[bk] + loc] = ((unsigned)(d & (BSZ - 1)) << 17) | (unsigned)s;
        }
    }
}

// pass 2 (fused): per-block bucket-count scan -> cbase; node hist+scan ->
// row_ptr, dinv, compact csr; epilogue = lin0 for this block's 256 nodes:
// A[node][c] = half(dinv * sum_k x[node][k]*W0[k][c])
__global__ __launch_bounds__(256) void k_build(const unsigned* __restrict__ bedges,
        const int* __restrict__ gcur, int* __restrict__ row_ptr,
        unsigned* __restrict__ csr, float* __restrict__ dinv,
        const float* __restrict__ x, const float* __restrict__ W0,
        __half* __restrict__ A, int n, int nb, int e) {
    __shared__ int hist[BSZ];
    __shared__ int cur[BSZ];
    __shared__ int sc[256];
    __shared__ int boffL[512];
    __shared__ float w0s[256];
    __shared__ float dinvs[BSZ];
    int b = blockIdx.x, t = threadIdx.x;
    int nodebase = b << BSH;

    // ---- bucket-count prefix scan (512 entries via 256 threads x 2) ----
    int c0 = (2 * t < nb) ? gcur[2 * t] : 0;
    int c1 = (2 * t + 1 < nb) ? gcur[2 * t + 1] : 0;
    int ps = c0 + c1;
    sc[t] = ps;
    w0s[t] = W0[t];
    __syncthreads();
    int acc = ps;
    for (int off = 1; off < 256; off <<= 1) {
        int xv = (t >= off) ? sc[t - off] : 0;
        __syncthreads();
        acc += xv;
        sc[t] = acc;
        __syncthreads();
    }
    boffL[2 * t] = acc - ps;
    boffL[2 * t + 1] = acc - ps + c0;
    if (t == 0 && b == 0) row_ptr[n] = e;
    __syncthreads();
    int cbase = boffL[b];
    int cnt = (b < nb) ? gcur[b] : 0;
    const unsigned* bed = bedges + (size_t)b * BCAP;

    // ---- node histogram ----
    hist[t] = 0;
    __syncthreads();
    int cnt4 = cnt & ~3;
    for (int jj = t * 4; jj < cnt4; jj += 1024) {
        uint4 p = *(const uint4*)(bed + jj);
        atomicAdd(&hist[p.x >> 17], 1); atomicAdd(&hist[p.y >> 17], 1);
        atomicAdd(&hist[p.z >> 17], 1); atomicAdd(&hist[p.w >> 17], 1);
    }
    for (int jj = cnt4 + t; jj < cnt; jj += 256)
        atomicAdd(&hist[bed[jj] >> 17], 1);
    __syncthreads();
    int a = hist[t];
    sc[t] = a;
    __syncthreads();
    int acc2 = a;
    for (int off = 1; off < 256; off <<= 1) {
        int xv = (t >= off) ? sc[t - off] : 0;
        __syncthreads();
        acc2 += xv;
        sc[t] = acc2;
        __syncthreads();
    }
    int e0 = cbase + acc2 - a;       // exclusive
    cur[t] = e0;
    float dv = rsqrtf((float)(a + 1));
    dinvs[t] = dv;
    int node = nodebase + t;
    if (node < n) { row_ptr[node] = e0; dinv[node] = dv; }
    __syncthreads();

    // ---- csr scatter (dst-sorted compact) ----
    for (int jj = t * 4; jj < cnt4; jj += 1024) {
        uint4 p = *(const uint4*)(bed + jj);
        int p0 = atomicAdd(&cur[p.x >> 17], 1); csr[p0] = p.x;
        int p1 = atomicAdd(&cur[p.y >> 17], 1); csr[p1] = p.y;
        int p2 = atomicAdd(&cur[p.z >> 17], 1); csr[p2] = p.z;
        int p3 = atomicAdd(&cur[p.w >> 17], 1); csr[p3] = p.w;
    }
    for (int jj = cnt4 + t; jj < cnt; jj += 256) {
        unsigned p = bed[jj];
        int pos = atomicAdd(&cur[p >> 17], 1);
        csr[pos] = p;
    }
    __syncthreads();

    // ---- fused lin0 for this block's nodes ----
    int wv = t >> 6, c = t & 63;
    for (int r = wv; r < BSZ; r += 4) {
        int nd = nodebase + r;
        if (nd >= n) continue;
        float4 xv = *(const float4*)(x + nd * 4);    // wave-uniform -> scalar loads
        float v = xv.x * w0s[c] + xv.y * w0s[64 + c]
                + xv.z * w0s[128 + c] + xv.w * w0s[192 + c];
        A[((size_t)nd << 6) + c] = __float2half(v * dinvs[r]);
    }
}

// ---------- layer compute ----------
// A: fp16, linear rows A[n*64+c] (128B per row); B: fp16 (BN stats in fp32)

// edge-parallel aggregation: one block per 64-node group, fp32 LDS accumulator.
// 16-lane groups: each lane loads 8B (4 halves) of the 128B row -> one wave
// instruction covers 4 edges; 16-deep unroll -> 16 gathers in flight per group.
// Register-accumulate runs of equal dst (sorted), flush 4 LDS atomics on change.
__global__ __launch_bounds__(256) void k_aggr(const int* __restrict__ row_ptr,
        const unsigned* __restrict__ pedges, const __half* __restrict__ A,
        const float* __restrict__ dinv, const float* __restrict__ bias,
        __half* __restrict__ B, float* __restrict__ stats, int n_nodes) {
    __shared__ float acc[64 * 65];
    __shared__ float ls[4][64], ls2[4][64];
    int t = threadIdx.x;
    for (int i = t; i < 64 * 65; i += 256) acc[i] = 0.f;
    int nodebase = blockIdx.x << 6;
    int nend = min(nodebase + 64, n_nodes);
    int ebeg = row_ptr[nodebase];
    int eend = row_ptr[nend];
    int nedges = eend - ebeg;
    __syncthreads();

    int wv = t >> 6, lane = t & 63;
    int sub = lane >> 4, ch = lane & 15;       // 16-lane group; ch*4 = channel base
    int s = wv * 4 + sub;                      // stream 0..15
    int sbeg = ebeg + (int)(((long long)nedges * s) >> 4);
    int send = ebeg + (int)(((long long)nedges * (s + 1)) >> 4);
    const uint2* A2 = (const uint2*)A;         // 16 uint2 per 64-half row

    float a0 = 0.f, a1 = 0.f, a2 = 0.f, a3 = 0.f;
    int cur = -1;

    #define FLUSH() if (cur >= 0) {                                            \
        int o_ = cur * 65 + (ch << 2);                                         \
        atomicAdd(&acc[o_ + 0], a0); atomicAdd(&acc[o_ + 1], a1);              \
        atomicAdd(&acc[o_ + 2], a2); atomicAdd(&acc[o_ + 3], a3); }

    #define PROC(P, U) {                                                       \
        int d_ = (int)((P) >> 17) & 63;                                        \
        if (d_ != cur) { FLUSH(); a0 = a1 = a2 = a3 = 0.f; cur = d_; }         \
        float2 f01_ = __half22float2(*(const __half2*)&(U).x);                 \
        float2 f23_ = __half22float2(*(const __half2*)&(U).y);                 \
        a0 += f01_.x; a1 += f01_.y; a2 += f23_.x; a3 += f23_.y; }

    int j = sbeg;
    for (; j + 16 <= send; j += 16) {
        unsigned p[16];
        uint2 u[16];
        #pragma unroll
        for (int k = 0; k < 16; ++k) p[k] = pedges[j + k];
        #pragma unroll
        for (int k = 0; k < 16; ++k)
            u[k] = A2[(((size_t)(p[k] & 0x1FFFFu)) << 4) + ch];
        #pragma unroll
        for (int k = 0; k < 16; ++k) PROC(p[k], u[k]);
    }
    for (; j < send; ++j) {
        unsigned p0 = pedges[j];
        uint2 u0 = A2[(((size_t)(p0 & 0x1FFFFu)) << 4) + ch];
        PROC(p0, u0);
    }
    FLUSH();
    #undef PROC
    #undef FLUSH
    __syncthreads();

    // finalize: wave wv handles rows wv, wv+4, ... ; lane = channel
    int c = lane;
    float st = 0.f, st2 = 0.f;
    for (int r = wv; r < 64; r += 4) {
        int node = nodebase + r;
        if (node < n_nodes) {
            float v = acc[r * 65 + c] + __half2float(A[((size_t)node << 6) + c]);
            v = dinv[node] * v + bias[c];
            B[((size_t)node << 6) + c] = __float2half(v);
            st += v; st2 += v * v;
        }
    }
    ls[wv][c] = st; ls2[wv][c] = st2;
    __syncthreads();
    if (t < 64) {
        atomAddF(&stats[t], ls[0][t] + ls[1][t] + ls[2][t] + ls[3][t]);
        atomAddF(&stats[64 + t], ls2[0][t] + ls2[1][t] + ls2[2][t] + ls2[3][t]);
    }
}

// A(half) <- dinv[n] * (relu(bn(B)) @ W1)   (BN0+ReLU fused into row staging)
// LDS-BW optimized: lane = (node_sub, channel-quad); per k-step one broadcast
// rows read + one ds_read_b128 of W1[k][quad*4..+3] + 4 FMA. 16 nodes/iter.
__global__ __launch_bounds__(256) void k_lin1(const __half* __restrict__ B,
        const float* __restrict__ W, const float* __restrict__ dinv,
        const float* __restrict__ stats, const float* __restrict__ g,
        const float* __restrict__ be, __half* __restrict__ A, int n_nodes) {
    __shared__ float w[HD * HD];
    __shared__ float rows[16][65];
    __shared__ float scb[64], shb[64];
    int t = threadIdx.x;
    for (int i = t; i < HD * HD; i += 256) w[i] = W[i];
    if (t < 64) {
        float inv_n = 1.0f / (float)n_nodes;
        float mu = stats[t] * inv_n;
        float var = stats[64 + t] * inv_n - mu * mu;
        float sc = g[t] * rsqrtf(var + EPS);
        scb[t] = sc;
        shb[t] = be[t] - mu * sc;
    }
    int wv = t >> 6, lane = t & 63;
    int nsub = lane >> 4, quad = lane & 15;
    int sr = t >> 4, sc0 = (t & 15) << 2;       // staging: 16 rows x 16 quads
    const float4* w4 = (const float4*)w;
    int ngroups = (n_nodes + 15) >> 4;
    for (int gidx = blockIdx.x; gidx < ngroups; gidx += gridDim.x) {
        __syncthreads();                 // rows reuse + first-iter w/scb barrier
        int nb0 = gidx << 4;
        {
            int nn = nb0 + sr;
            float f0 = 0.f, f1 = 0.f, f2 = 0.f, f3 = 0.f;
            if (nn < n_nodes) {
                uint2 u = *(const uint2*)(B + ((size_t)nn << 6) + sc0);
                float2 p01 = __half22float2(*(const __half2*)&u.x);
                float2 p23 = __half22float2(*(const __half2*)&u.y);
                f0 = p01.x; f1 = p01.y; f2 = p23.x; f3 = p23.y;
            }
            rows[sr][sc0 + 0] = fmaxf(scb[sc0 + 0] * f0 + shb[sc0 + 0], 0.f);
            rows[sr][sc0 + 1] = fmaxf(scb[sc0 + 1] * f1 + shb[sc0 + 1], 0.f);
            rows[sr][sc0 + 2] = fmaxf(scb[sc0 + 2] * f2 + shb[sc0 + 2], 0.f);
            rows[sr][sc0 + 3] = fmaxf(scb[sc0 + 3] * f3 + shb[sc0 + 3], 0.f);
        }
        __syncthreads();
        int r = (wv << 2) + nsub;
        int node = nb0 + r;
        if (node < n_nodes) {
            float a0 = 0.f, a1 = 0.f, a2 = 0.f, a3 = 0.f;
            #pragma unroll 8
            for (int k = 0; k < 64; ++k) {
                float hv = rows[r][k];
                float4 wq = w4[(k << 4) + quad];
                a0 = fmaf(hv, wq.x, a0); a1 = fmaf(hv, wq.y, a1);
                a2 = fmaf(hv, wq.z, a2); a3 = fmaf(hv, wq.w, a3);
            }
            float dv = dinv[node];
            __half2 h01 = __floats2half2_rn(a0 * dv, a1 * dv);
            __half2 h23 = __floats2half2_rn(a2 * dv, a3 * dv);
            uint2 uu;
            uu.x = *(unsigned*)&h01;
            uu.y = *(unsigned*)&h23;
            *(uint2*)(A + ((size_t)node << 6) + (quad << 2)) = uu;
        }
    }
}

// fused MLP head, weight-coalesced: block = 32 nodes, wave = 8 nodes,
// lane = OUTPUT channel -> Wm0[k*64+j] is a coalesced 256B vector load;
// h[k] comes from LDS broadcast. m1: half-wave = 4 nodes x 32 channels.
// m2: shuffle reduce over the 32-lane half.
__global__ __launch_bounds__(256) void k_mlp(const __half* __restrict__ B,
        const float* __restrict__ stats, const float* __restrict__ g,
        const float* __restrict__ be,
        const float* __restrict__ Wm0, const float* __restrict__ bm0,
        const float* __restrict__ Wm1, const float* __restrict__ bm1,
        const float* __restrict__ Wm2, const float* __restrict__ bm2,
        float* __restrict__ out, int n_nodes) {
    __shared__ float rows[32][66];      // 66: even stride, 8B-aligned float2
    __shared__ float scb[64], shb[64];
    int t = threadIdx.x;
    if (t < 64) {
        float inv_n = 1.0f / (float)n_nodes;
        float mu = stats[t] * inv_n;
        float var = stats[64 + t] * inv_n - mu * mu;
        float sc = g[t] * rsqrtf(var + EPS);
        scb[t] = sc;
        shb[t] = be[t] - mu * sc;
    }
    __syncthreads();
    int nbase = blockIdx.x * 32;
    {   // staging: 32 rows x 8 threads/row, 8 halves (16B) per thread
        int r = t >> 3, c0 = (t & 7) << 3;
        int nn = nbase + r;
        float f[8];
        if (nn < n_nodes) {
            uint4 u = *(const uint4*)(B + ((size_t)nn << 6) + c0);
            float2 p01 = __half22float2(*(const __half2*)&u.x);
            float2 p23 = __half22float2(*(const __half2*)&u.y);
            float2 p45 = __half22float2(*(const __half2*)&u.z);
            float2 p67 = __half22float2(*(const __half2*)&u.w);
            f[0] = p01.x; f[1] = p01.y; f[2] = p23.x; f[3] = p23.y;
            f[4] = p45.x; f[5] = p45.y; f[6] = p67.x; f[7] = p67.y;
        } else {
            #pragma unroll
            for (int k = 0; k < 8; ++k) f[k] = 0.f;
        }
        #pragma unroll
        for (int k = 0; k < 8; ++k)
            rows[r][c0 + k] = fmaxf(scb[c0 + k] * f[k] + shb[c0 + k], 0.f);
    }
    __syncthreads();

    int w = t >> 6, j = t & 63;
    int rb = w * 8;
    // ---- m0: 8 nodes/wave, lane = output channel ----
    float acc0[8];
    float b0j = bm0[j];
    #pragma unroll
    for (int i = 0; i < 8; ++i) acc0[i] = b0j;
    #pragma unroll 4
    for (int k = 0; k < 64; k += 2) {
        float wv0 = Wm0[k * 64 + j];
        float wv1 = Wm0[(k + 1) * 64 + j];
        #pragma unroll
        for (int i = 0; i < 8; ++i) {
            float2 hv = *(const float2*)&rows[rb + i][k];
            acc0[i] = fmaf(hv.x, wv0, acc0[i]);
            acc0[i] = fmaf(hv.y, wv1, acc0[i]);
        }
    }
    #pragma unroll
    for (int i = 0; i < 8; ++i) rows[rb + i][j] = fmaxf(acc0[i], 0.f);
    __syncthreads();
    // ---- m1: half-wave h -> nodes rb+h*4.., ch2 = output channel ----
    int h = j >> 5, ch2 = j & 31;
    int rb1 = rb + h * 4;
    float acc2[4];
    float b1j = bm1[ch2];
    #pragma unroll
    for (int i = 0; i < 4; ++i) acc2[i] = b1j;
    #pragma unroll 4
    for (int k = 0; k < 64; k += 2) {
        float wv0 = Wm1[k * 32 + ch2];
        float wv1 = Wm1[(k + 1) * 32 + ch2];
        #pragma unroll
        for (int i = 0; i < 4; ++i) {
            float2 hv = *(const float2*)&rows[rb1 + i][k];
            acc2[i] = fmaf(hv.x, wv0, acc2[i]);
            acc2[i] = fmaf(hv.y, wv1, acc2[i]);
        }
    }
    // ---- m2: per-node dot over 32 channels via shuffle reduce ----
    float wm2 = Wm2[ch2];
    float z[4];
    #pragma unroll
    for (int i = 0; i < 4; ++i) z[i] = fmaxf(acc2[i], 0.f) * wm2;
    #pragma unroll
    for (int d = 1; d < 32; d <<= 1) {
        #pragma unroll
        for (int i = 0; i < 4; ++i) z[i] += __shfl_xor(z[i], d, 64);
    }
    if (ch2 == 0) {
        float bb = bm2[0];
        #pragma unroll
        for (int i = 0; i < 4; ++i) {
            int nn = nbase + rb1 + i;
            if (nn < n_nodes)
                out[nn] = 1.0f / (1.0f + __expf(-(z[i] + bb)));
        }
    }
}

extern "C" void kernel_launch(void* const* d_in, const int* in_sizes, int n_in,
                              void* d_out, int out_size, void* d_ws, size_t ws_size,
                              hipStream_t stream) {
    const float* x   = (const float*)d_in[0];
    const int*   src = (const int*)d_in[1];
    const int*   dst = (const int*)d_in[2];
    const float* W0  = (const float*)d_in[3];
    const float* b0  = (const float*)d_in[4];
    const float* W1  = (const float*)d_in[5];
    const float* b1  = (const float*)d_in[6];
    const float* g0  = (const float*)d_in[7];
    const float* be0 = (const float*)d_in[8];
    const float* g1  = (const float*)d_in[9];
    const float* be1 = (const float*)d_in[10];
    const float* Wm0 = (const float*)d_in[11];
    const float* bm0 = (const float*)d_in[12];
    const float* Wm1 = (const float*)d_in[13];
    const float* bm1 = (const float*)d_in[14];
    const float* Wm2 = (const float*)d_in[15];
    const float* bm2 = (const float*)d_in[16];

    int n = in_sizes[0] / 4;
    int e = in_sizes[1];
    float* out = (float*)d_out;

    int nb = (n + BSZ - 1) >> BSH;            // 391 buckets for n=100k

    char* ws = (char*)d_ws;
    auto alignup = [](size_t v) { return (v + 255) & ~(size_t)255; };
    size_t o = 0;
    int*      gcur    = (int*)(ws + o);      o += alignup(512 * 4);   // contiguous with stats
    float*    stats   = (float*)(ws + o);    o += alignup(256 * 4);
    int*      row_ptr = (int*)(ws + o);      o += alignup((size_t)(n + 1) * 4);
    float*    dinv    = (float*)(ws + o);    o += alignup((size_t)n * 4);
    unsigned* bedges  = (unsigned*)(ws + o); o += alignup((size_t)nb * BCAP * 4);
    unsigned* csr     = (unsigned*)(ws + o); o += alignup((size_t)e * 4);
    __half*   A       = (__half*)(ws + o);   o += alignup((size_t)n * 64 * 2);
    __half*   B       = (__half*)(ws + o);

    int ntiles = (e + T1 - 1) / T1;           // 782 blocks
    int gMLP   = (n + 31) / 32;
    int gAGG   = (n + 63) / 64;               // one block per 64-node group

    (void)hipMemsetAsync(gcur, 0, (512 + 256) * 4, stream);   // gcur + stats

    // ---- CSR build + lin0 (fused; once, reused by both layers) ----
    k_bucket<<<ntiles, 256, 0, stream>>>(src, dst, gcur, bedges, e, nb);
    k_build<<<nb, 256, 0, stream>>>(bedges, gcur, row_ptr, csr, dinv,
                                    x, W0, A, n, nb, e);

    // ---- layer 1 ----
    k_aggr<<<gAGG, 256, 0, stream>>>(row_ptr, csr, A, dinv, b0, B, stats, n);

    // ---- layer 2 (BN0+ReLU fused into lin1) ----
    k_lin1<<<2048, 256, 0, stream>>>(B, W1, dinv, stats, g0, be0, A, n);
    k_aggr<<<gAGG, 256, 0, stream>>>(row_ptr, csr, A, dinv, b1, B, stats + 128, n);

    // ---- MLP head (BN1+ReLU fused) ----
    k_mlp<<<gMLP, 256, 0, stream>>>(B, stats + 128, g1, be1,
                                    Wm0, bm0, Wm1, bm1, Wm2, bm2, out, n);
}